// Round 12
// baseline (1461.658 us; speedup 1.0000x reference)
//
#include <hip/hip_runtime.h>
#include <math.h>

#define Bc 8
#define Nc 4096
#define CINc 128
#define COUTc 256
#define Sc 1024
#define Kc 24
#define TCHc 256
#define Mc 32
#define Hc 4
#define HDc 64
#define MBAT (Sc*Kc)      // rows per batch in Local stage: 24576

#define BN_SCALE_F 0.9999950000374997f

typedef __attribute__((ext_vector_type(8))) short bf16x8;
typedef __attribute__((ext_vector_type(4))) float f32x4;

__device__ __forceinline__ float b2f(short s){
  unsigned int u = ((unsigned int)(unsigned short)s) << 16;
  union { unsigned int u; float f; } c; c.u = u; return c.f;
}
__device__ __forceinline__ short f2b(float f){
  union { unsigned int u; float f; } c; c.f = f;
  unsigned int u = c.u;
  unsigned int r = (u + 0x7fffu + ((u >> 16) & 1u)) >> 16;
  return (short)(r & 0xffffu);
}
__device__ __forceinline__ float gelu_f(float v){
  return 0.5f * v * (1.f + erff(v * 0.7071067811865475f));
}
__device__ __forceinline__ bf16x8 ld8cvt(const short* p){ return *(const bf16x8*)p; }
__device__ __forceinline__ bf16x8 ld8cvt(const float* p){
  f32x4 a = *(const f32x4*)p; f32x4 b = *(const f32x4*)(p+4);
  bf16x8 r;
  r[0]=f2b(a[0]); r[1]=f2b(a[1]); r[2]=f2b(a[2]); r[3]=f2b(a[3]);
  r[4]=f2b(b[0]); r[5]=f2b(b[1]); r[6]=f2b(b[2]); r[7]=f2b(b[3]);
  return r;
}
__device__ __forceinline__ float rdval(const float* p){ return *p; }
__device__ __forceinline__ float rdval(const short* p){ return b2f(*p); }
__device__ __forceinline__ void wrval(float* p, float v){ *p = v; }
__device__ __forceinline__ void wrval(short* p, float v){ *p = f2b(v); }

// async global->LDS, 16B per lane (dest follows lane order: base + lane*16B)
__device__ __forceinline__ void gl_lds16(const short* g, short* l){
  __builtin_amdgcn_global_load_lds(
     (const __attribute__((address_space(1))) void*)g,
     (__attribute__((address_space(3))) void*)l, 16, 0, 0);
}

template<int CTRL>
__device__ __forceinline__ double dpp_max_f64(double v){
  long long x = __double_as_longlong(v);
  int lo = (int)(unsigned int)(x & 0xFFFFFFFFLL);
  int hi = (int)(unsigned int)((unsigned long long)x >> 32);
  int plo = __builtin_amdgcn_update_dpp(lo, lo, CTRL, 0xF, 0xF, false);
  int phi = __builtin_amdgcn_update_dpp(hi, hi, CTRL, 0xF, 0xF, false);
  double p = __longlong_as_double((long long)(((unsigned long long)(unsigned int)phi << 32)
                                              | (unsigned int)plo));
  return fmax(v, p);
}
template<int CTRL>
__device__ __forceinline__ float dpp_min_f32(float v){
  int x = __float_as_int(v);
  int p = __builtin_amdgcn_update_dpp(x, x, CTRL, 0xF, 0xF, false);
  return fminf(v, __int_as_float(p));
}
template<int CTRL>
__device__ __forceinline__ unsigned dpp_min_u32(unsigned v){
  int p = __builtin_amdgcn_update_dpp((int)v, (int)v, CTRL, 0xF, 0xF, false);
  unsigned pu = (unsigned)p;
  return v < pu ? v : pu;
}

// ---------------- prep mega-kernel (256 thr): fps(8) | tx(4096) | cvt(64) | dd(128)
#define PREP_FPS 8
#define PREP_TX 4096
#define PREP_CVT 64
#define PREP_DD 128
#define PREP_TOTAL (PREP_FPS+PREP_TX+PREP_CVT+PREP_DD)

__global__ __launch_bounds__(256) void prep_kernel(
    const float* __restrict__ xyz, const int* __restrict__ far0, int* __restrict__ fps_idx,
    const float* __restrict__ x, short* __restrict__ xT,
    const float* __restrict__ Wproj, const float* __restrict__ Wl1, const float* __restrict__ Wl2,
    const float* __restrict__ Wc1, const float* __restrict__ Wc2,
    const float* __restrict__ Wk, const float* __restrict__ Wv,
    short* __restrict__ wbf, float* __restrict__ dd){
  __shared__ double smem[6176];   // 49408 B: fps sx/sy/sz (48KB) + pwave; reused by others
  int bid = blockIdx.x, tid = threadIdx.x;
  if(bid < PREP_FPS){
    // ---- FPS (round-6/10 proven logic, 256 thr, 16 pts/thread) ----
    int b = bid;
    float* sx = (float*)smem;
    float* sy = sx + Nc;
    float* sz = sy + Nc;
    double* pwave = smem + (Nc*12)/8;   // [2][4]
    const float* xb = xyz + (size_t)b*Nc*3;
    for(int i=tid; i<Nc; i+=256){
      const float* p = xb + i*3;
      sx[i]=p[0]; sy[i]=p[1]; sz[i]=p[2];
    }
    __syncthreads();
    float px[16], py[16], pz[16], dmin[16];
    unsigned int lokey[16];
#pragma unroll
    for(int j=0;j<16;j++){
      int n = tid + 256*j;
      px[j]=sx[n]; py[j]=sy[n]; pz[j]=sz[n];
      dmin[j]=1e10f;
      lokey[j]=(unsigned int)((Nc-1) - n);
    }
    int winner = far0[b] & (Nc-1);
    int* out = fps_idx + b*Sc;
    for(int it=0; it<Sc; it++){
      if(tid==0) out[it] = winner;
      float cx=sx[winner], cy=sy[winner], cz=sz[winner];
      double key[16];
#pragma unroll
      for(int j=0;j<16;j++){
        float dx = __fsub_rn(px[j], cx);
        float dy = __fsub_rn(py[j], cy);
        float dz = __fsub_rn(pz[j], cz);
        float d = __fadd_rn(__fadd_rn(__fmul_rn(dx,dx), __fmul_rn(dy,dy)), __fmul_rn(dz,dz));
        dmin[j] = fminf(dmin[j], d);
        unsigned long long k = (((unsigned long long)__float_as_uint(dmin[j])) << 32) | lokey[j];
        key[j] = __longlong_as_double((long long)k);
      }
#pragma unroll
      for(int st=8; st>0; st>>=1)
#pragma unroll
        for(int j=0;j<st;j++) key[j] = fmax(key[j], key[j+st]);
      double kv = key[0];
      kv = dpp_max_f64<0x111>(kv);
      kv = dpp_max_f64<0x112>(kv);
      kv = dpp_max_f64<0x114>(kv);
      kv = dpp_max_f64<0x118>(kv);
      kv = dpp_max_f64<0x142>(kv);
      kv = dpp_max_f64<0x143>(kv);
      int p = it & 1;
      if((tid & 63) == 63) pwave[p*4 + (tid>>6)] = kv;
      __syncthreads();
      double k0 = pwave[p*4+0], k1 = pwave[p*4+1], k2 = pwave[p*4+2], k3 = pwave[p*4+3];
      double kb = fmax(fmax(k0,k1), fmax(k2,k3));
      unsigned long long kbits = (unsigned long long)__double_as_longlong(kb);
      winner = (Nc-1) - (int)(kbits & 0xFFFFFFFFULL);
    }
  } else if(bid < PREP_FPS+PREP_TX){
    int t = bid - PREP_FPS;
    int b = t >> 9;
    int rem = t & 511;
    int n0 = (rem & 127) * 32;
    int c0 = (rem >> 7) * 32;
    short (*tile)[33] = (short(*)[33])smem;
    int tx = tid & 31, ty = tid >> 5;
#pragma unroll
    for(int i=0;i<32;i+=8)
      tile[ty+i][tx] = f2b(x[((size_t)b*CINc + (c0+ty+i))*Nc + n0+tx]);
    __syncthreads();
#pragma unroll
    for(int i=0;i<32;i+=8)
      xT[((size_t)b*Nc + (n0+ty+i))*CINc + c0+tx] = tile[tx][ty+i];
  } else if(bid < PREP_FPS+PREP_TX+PREP_CVT){
    int gid = (bid - PREP_FPS - PREP_TX)*256 + tid;
    const int stride = PREP_CVT*256;
    short* p = wbf;
    for(int i=gid; i<COUTc*CINc; i+=stride) p[i] = f2b(Wproj[i]);
    p += COUTc*CINc;
    for(int i=gid; i<COUTc*COUTc; i+=stride) p[i] = f2b(Wl1[i]);
    p += COUTc*COUTc;
    for(int i=gid; i<COUTc*COUTc; i+=stride) p[i] = f2b(Wl2[i]);
    p += COUTc*COUTc;
    for(int i=gid; i<COUTc*COUTc; i+=stride) p[i] = f2b(Wc1[i]);
    p += COUTc*COUTc;
    for(int i=gid; i<COUTc*COUTc; i+=stride) p[i] = f2b(Wc2[i]);
    p += COUTc*COUTc;
    for(int i=gid; i<TCHc*COUTc; i+=stride) p[i] = f2b(Wk[i]);
    p += TCHc*COUTc;
    for(int i=gid; i<TCHc*COUTc; i+=stride) p[i] = f2b(Wv[i]);
  } else {
    int i = (bid - PREP_FPS - PREP_TX - PREP_CVT)*256 + tid;
    const float* p = xyz + (size_t)i*3;
    float xx=p[0], yy=p[1], zz=p[2];
    dd[i] = __fadd_rn(__fadd_rn(__fmul_rn(xx,xx),__fmul_rn(yy,yy)),__fmul_rn(zz,zz));
  }
}

// ---------------- KNN: block per (b,s); DPP-based argmin rounds ------------
__global__ __launch_bounds__(256) void knn_kernel(const float* __restrict__ xyz,
                                                  const int* __restrict__ fps_idx,
                                                  const float* __restrict__ dd,
                                                  int* __restrict__ knn_idx,
                                                  float* __restrict__ out0){
  int bs = blockIdx.x, tid = threadIdx.x;
  int b = bs >> 10;
  __shared__ float pv[4]; __shared__ int pi[4];
  int qn = fps_idx[bs] & (Nc-1);
  const float* q = xyz + ((size_t)b*Nc + qn)*3;
  float sx = q[0], sy = q[1], sz = q[2];
  if(tid < 3) out0[bs*3 + tid] = q[tid];
  float ss = __fadd_rn(__fadd_rn(__fmul_rn(sx,sx),__fmul_rn(sy,sy)),__fmul_rn(sz,sz));
  const float* xb = xyz + (size_t)b*Nc*3;
  const float* db = dd + b*Nc;
  float dv[16];
#pragma unroll
  for(int j=0;j<16;j++){
    int n = tid + 256*j;
    float xx=xb[n*3], yy=xb[n*3+1], zz=xb[n*3+2];
    float e = __fmul_rn(sx,xx);
    e = __fadd_rn(e, __fmul_rn(sy,yy));
    e = __fadd_rn(e, __fmul_rn(sz,zz));
    dv[j] = __fadd_rn(__fadd_rn(__fmul_rn(-2.f,e), ss), db[n]);
  }
  int* ob = knn_idx + (size_t)bs*Kc;
  for(int k=0;k<Kc;k++){
    float bvv = dv[0];
#pragma unroll
    for(int j=1;j<16;j++) bvv = fminf(bvv, dv[j]);
    bvv = dpp_min_f32<0x111>(bvv);
    bvv = dpp_min_f32<0x112>(bvv);
    bvv = dpp_min_f32<0x114>(bvv);
    bvv = dpp_min_f32<0x118>(bvv);
    bvv = dpp_min_f32<0x142>(bvv);
    bvv = dpp_min_f32<0x143>(bvv);
    if((tid&63)==63) pv[tid>>6] = bvv;
    __syncthreads();
    float vmin = fminf(fminf(pv[0],pv[1]), fminf(pv[2],pv[3]));
    unsigned bi = 0xFFFFFFFFu;
#pragma unroll
    for(int j=0;j<16;j++){
      unsigned n = (unsigned)(tid + 256*j);
      if(dv[j]==vmin && n < bi) bi = n;
    }
    bi = dpp_min_u32<0x111>(bi);
    bi = dpp_min_u32<0x112>(bi);
    bi = dpp_min_u32<0x114>(bi);
    bi = dpp_min_u32<0x118>(bi);
    bi = dpp_min_u32<0x142>(bi);
    bi = dpp_min_u32<0x143>(bi);
    if((tid&63)==63) pi[tid>>6] = (int)bi;
    __syncthreads();
    unsigned i0=(unsigned)pi[0], i1=(unsigned)pi[1], i2=(unsigned)pi[2], i3=(unsigned)pi[3];
    unsigned m01 = i0<i1?i0:i1, m23 = i2<i3?i2:i3;
    unsigned win = m01<m23?m01:m23;
    if(tid==0) ob[k] = (int)(win & (Nc-1));
#pragma unroll
    for(int j=0;j<16;j++) if((int)win == tid + 256*j) dv[j] = 3.4e38f;
  }
}

// ---------------- 128x128 MFMA GEMM, A/W bf16 ------------------------------
template<int HAS_BN, int HAS_GELU, int HAS_RES, typename TRES>
__global__ __launch_bounds__(256) void gemm128(
    const short* __restrict__ A, const short* __restrict__ W,
    const float* __restrict__ g, const float* __restrict__ bias,
    const TRES* __restrict__ Res, short* __restrict__ Out,
    int Nn, int Kk){
  __shared__ short As[128*32];
  __shared__ short Bs[128*32];
  int bm = blockIdx.y*128, bn = blockIdx.x*128;
  int tid = threadIdx.x;
  int wave = tid>>6, lane = tid&63, quad = lane>>4, l16 = lane&15;
  int wr = (wave>>1)*64, wc = (wave&1)*64;
  f32x4 acc[4][4];
#pragma unroll
  for(int i=0;i<4;i++)
#pragma unroll
    for(int j=0;j<4;j++) acc[i][j] = (f32x4){0.f,0.f,0.f,0.f};
  int sr = tid>>2, scc = (tid&3)*8;
  const short* Ap = A + (size_t)(bm+sr)*Kk + scc;
  const short* Wp = W + (size_t)(bn+sr)*Kk + scc;
  for(int k0=0; k0<Kk; k0+=32){
    gl_lds16(Ap + k0,                    As + tid*8);
    gl_lds16(Ap + k0 + (size_t)64*Kk,    As + 2048 + tid*8);
    gl_lds16(Wp + k0,                    Bs + tid*8);
    gl_lds16(Wp + k0 + (size_t)64*Kk,    Bs + 2048 + tid*8);
    __syncthreads();
    bf16x8 af[4], bfr[4];
#pragma unroll
    for(int mt=0; mt<4; mt++) af[mt]  = *(const bf16x8*)&As[(wr+mt*16+l16)*32 + quad*8];
#pragma unroll
    for(int nt=0; nt<4; nt++) bfr[nt] = *(const bf16x8*)&Bs[(wc+nt*16+l16)*32 + quad*8];
#pragma unroll
    for(int mt=0; mt<4; mt++)
#pragma unroll
      for(int nt=0; nt<4; nt++)
        acc[mt][nt] = __builtin_amdgcn_mfma_f32_16x16x32_bf16(af[mt], bfr[nt], acc[mt][nt], 0, 0, 0);
    __syncthreads();
  }
#pragma unroll
  for(int nt=0; nt<4; nt++){
    int col = bn + wc + nt*16 + l16;
    float gs = 0.f, bs_ = 0.f;
    if(HAS_BN){ gs = g[col] * BN_SCALE_F; bs_ = bias[col]; }
#pragma unroll
    for(int mt=0; mt<4; mt++){
#pragma unroll
      for(int r2=0;r2<4;r2++){
        int row = bm + wr + mt*16 + quad*4 + r2;
        float v = acc[mt][nt][r2];
        if(HAS_BN) v = v*gs + bs_;
        if(HAS_RES) v += rdval(Res + (size_t)row*Nn + col);
        if(HAS_GELU) v = gelu_f(v);
        Out[(size_t)row*Nn + col] = f2b(v);
      }
    }
  }
}

// ------- proj 128x128: gathered edge A, W via DMA; rows offset by R0 -------
__global__ __launch_bounds__(256) void proj128(
    const short* __restrict__ xT, const int* __restrict__ knn_idx, const int* __restrict__ fps_idx,
    const short* __restrict__ W, const float* __restrict__ g, const float* __restrict__ bias,
    short* __restrict__ Out, int R0){
  __shared__ short As[128*32];
  __shared__ short Bs[128*32];
  int bm = blockIdx.y*128, bn = blockIdx.x*128;
  int tid = threadIdx.x;
  int wave = tid>>6, lane = tid&63, quad = lane>>4, l16 = lane&15;
  int wr = (wave>>1)*64, wc = (wave&1)*64;
  f32x4 acc[4][4];
#pragma unroll
  for(int i=0;i<4;i++)
#pragma unroll
    for(int j=0;j<4;j++) acc[i][j] = (f32x4){0.f,0.f,0.f,0.f};
  int sr = tid>>2, scc = (tid&3)*8;
  int Rg0 = R0 + bm + sr, Rg1 = Rg0 + 64;
  int b0 = Rg0 / (Sc*Kc), b1 = Rg1 / (Sc*Kc);
  int nk0 = knn_idx[Rg0] & (Nc-1), nk1 = knn_idx[Rg1] & (Nc-1);
  int nc0 = fps_idx[Rg0 / Kc] & (Nc-1), nc1 = fps_idx[Rg1 / Kc] & (Nc-1);
  const short* pk0 = xT + ((size_t)b0*Nc + nk0)*CINc + scc;
  const short* pc0 = xT + ((size_t)b0*Nc + nc0)*CINc + scc;
  const short* pk1 = xT + ((size_t)b1*Nc + nk1)*CINc + scc;
  const short* pc1 = xT + ((size_t)b1*Nc + nc1)*CINc + scc;
  const short* Wp  = W + (size_t)(bn+sr)*CINc + scc;
  for(int k0=0; k0<CINc; k0+=32){
    gl_lds16(Wp + k0,                      Bs + tid*8);
    gl_lds16(Wp + k0 + (size_t)64*CINc,    Bs + 2048 + tid*8);
    bf16x8 vk = *(const bf16x8*)(pk0 + k0);
    bf16x8 vc = *(const bf16x8*)(pc0 + k0);
    bf16x8 e0, e1;
#pragma unroll
    for(int i=0;i<8;i++) e0[i] = f2b(__fsub_rn(b2f(vk[i]), b2f(vc[i])));
    vk = *(const bf16x8*)(pk1 + k0);
    vc = *(const bf16x8*)(pc1 + k0);
#pragma unroll
    for(int i=0;i<8;i++) e1[i] = f2b(__fsub_rn(b2f(vk[i]), b2f(vc[i])));
    *(bf16x8*)&As[tid*8] = e0;
    *(bf16x8*)&As[2048 + tid*8] = e1;
    __syncthreads();
    bf16x8 af[4], bfr[4];
#pragma unroll
    for(int mt=0; mt<4; mt++) af[mt]  = *(const bf16x8*)&As[(wr+mt*16+l16)*32 + quad*8];
#pragma unroll
    for(int nt=0; nt<4; nt++) bfr[nt] = *(const bf16x8*)&Bs[(wc+nt*16+l16)*32 + quad*8];
#pragma unroll
    for(int mt=0; mt<4; mt++)
#pragma unroll
      for(int nt=0; nt<4; nt++)
        acc[mt][nt] = __builtin_amdgcn_mfma_f32_16x16x32_bf16(af[mt], bfr[nt], acc[mt][nt], 0, 0, 0);
    __syncthreads();
  }
#pragma unroll
  for(int nt=0; nt<4; nt++){
    int col = bn + wc + nt*16 + l16;
    float gs = g[col] * BN_SCALE_F, bs_ = bias[col];
#pragma unroll
    for(int mt=0; mt<4; mt++){
#pragma unroll
      for(int r2=0;r2<4;r2++){
        int row = bm + wr + mt*16 + quad*4 + r2;
        float v = acc[mt][nt][r2]*gs + bs_;
        Out[(size_t)row*COUTc + col] = f2b(gelu_f(v));
      }
    }
  }
}

// -- l2 GEMM 96x128 + residual + gelu + max over k (BM=96 = 4 k-groups) -----
__global__ __launch_bounds__(256) void l2max96(
    const short* __restrict__ A, const short* __restrict__ W,
    const float* __restrict__ g, const float* __restrict__ bias,
    const short* __restrict__ Hres, short* __restrict__ Fout, int R0){
  __shared__ __align__(16) char sbuf[96*129*4];   // 49536 B, unioned
  short* As = (short*)sbuf;                        // 96x32 = 6144 B
  short* Bs = (short*)(sbuf + 6144);               // 128x32 = 8192 B
  float (*sm)[129] = (float(*)[129])sbuf;          // 96x129 f32 (after K-loop)
  int bm = blockIdx.y*96, bn = blockIdx.x*128;
  int tid = threadIdx.x;
  int wave = tid>>6, lane = tid&63, quad = lane>>4, l16 = lane&15;
  int wr = (wave>>1)*48, wc = (wave&1)*64;
  f32x4 acc[3][4];
#pragma unroll
  for(int i=0;i<3;i++)
#pragma unroll
    for(int j=0;j<4;j++) acc[i][j] = (f32x4){0.f,0.f,0.f,0.f};
  int sr = tid>>2, scc = (tid&3)*8;
  const short* Ap = A + (size_t)(bm+sr)*COUTc + scc;
  const short* Wp = W + (size_t)(bn+sr)*COUTc + scc;
  for(int k0=0; k0<COUTc; k0+=32){
    gl_lds16(Ap + k0, As + tid*8);
    if(tid < 128) gl_lds16(Ap + k0 + (size_t)64*COUTc, As + 2048 + tid*8);
    gl_lds16(Wp + k0, Bs + tid*8);
    gl_lds16(Wp + k0 + (size_t)64*COUTc, Bs + 2048 + tid*8);
    __syncthreads();
    bf16x8 af[3], bfr[4];
#pragma unroll
    for(int mt=0; mt<3; mt++) af[mt]  = *(const bf16x8*)&As[(wr+mt*16+l16)*32 + quad*8];
#pragma unroll
    for(int nt=0; nt<4; nt++) bfr[nt] = *(const bf16x8*)&Bs[(wc+nt*16+l16)*32 + quad*8];
#pragma unroll
    for(int mt=0; mt<3; mt++)
#pragma unroll
      for(int nt=0; nt<4; nt++)
        acc[mt][nt] = __builtin_amdgcn_mfma_f32_16x16x32_bf16(af[mt], bfr[nt], acc[mt][nt], 0, 0, 0);
    __syncthreads();
  }
#pragma unroll
  for(int nt=0; nt<4; nt++){
    int col = bn + wc + nt*16 + l16;
    float gs = g[col] * BN_SCALE_F, bs_ = bias[col];
#pragma unroll
    for(int mt=0; mt<3; mt++){
#pragma unroll
      for(int r2=0;r2<4;r2++){
        int rl = wr + mt*16 + quad*4 + r2;
        float v = acc[mt][nt][r2]*gs + bs_;
        v += b2f(Hres[(size_t)(bm+rl)*COUTc + col]);
        sm[rl][wc + nt*16 + l16] = gelu_f(v);
      }
    }
  }
  __syncthreads();
#pragma unroll
  for(int rep=0; rep<2; rep++){
    int idx = rep*256 + tid;
    int gg = idx >> 7, col = idx & 127;
    float mx = -3.4e38f;
#pragma unroll
    for(int kk=0; kk<Kc; kk++) mx = fmaxf(mx, sm[gg*Kc + kk][col]);
    int srow = R0/Kc + blockIdx.y*4 + gg;
    Fout[(size_t)srow*COUTc + bn + col] = f2b(mx);
  }
}

// ------- 64x64 MFMA GEMM, A & W bf16, both staged via global_load_lds ------
template<int HAS_BN, int HAS_GELU, int HAS_RES, typename TRES, typename TOUT>
__global__ __launch_bounds__(256) void gemm64d(
    const short* __restrict__ A, const short* __restrict__ W,
    const float* __restrict__ g, const float* __restrict__ bias,
    const TRES* __restrict__ Res, TOUT* __restrict__ Out,
    int Nn, int Kk){
  __shared__ short As[64*32];
  __shared__ short Bs[64*32];
  int bm = blockIdx.y*64, bn = blockIdx.x*64;
  int tid = threadIdx.x;
  int wave = tid >> 6, lane = tid & 63, quad = lane >> 4, l16 = lane & 15;
  f32x4 acc[4];
#pragma unroll
  for(int i=0;i<4;i++) acc[i] = (f32x4){0.f,0.f,0.f,0.f};
  const short* Ap = A + (size_t)(bm + (tid>>2))*Kk + (tid&3)*8;
  const short* Wp = W + (size_t)(bn + (tid>>2))*Kk + (tid&3)*8;
  for(int k0=0; k0<Kk; k0+=32){
    gl_lds16(Ap + k0, As + tid*8);
    gl_lds16(Wp + k0, Bs + tid*8);
    __syncthreads();
    bf16x8 a = *(const bf16x8*)&As[(wave*16 + l16)*32 + quad*8];
#pragma unroll
    for(int ct=0; ct<4; ct++){
      bf16x8 bb = *(const bf16x8*)&Bs[(ct*16 + l16)*32 + quad*8];
      acc[ct] = __builtin_amdgcn_mfma_f32_16x16x32_bf16(a, bb, acc[ct], 0, 0, 0);
    }
    __syncthreads();
  }
#pragma unroll
  for(int ct=0; ct<4; ct++){
    int col = bn + ct*16 + l16;
    float gs = 0.f, bs_ = 0.f;
    if(HAS_BN){ gs = g[col] * BN_SCALE_F; bs_ = bias[col]; }
#pragma unroll
    for(int r2=0;r2<4;r2++){
      int row = bm + wave*16 + quad*4 + r2;
      float v = acc[ct][r2];
      if(HAS_BN) v = v*gs + bs_;
      if(HAS_RES) v += rdval(Res + (size_t)row*Nn + col);
      if(HAS_GELU) v = gelu_f(v);
      wrval(Out + (size_t)row*Nn + col, v);
    }
  }
}

// ---------------- generic bf16 MFMA GEMM (64x64), f32 W --------------------
template<typename TA, typename TRES, typename TOUT, int HAS_BN, int HAS_GELU, int HAS_RES>
__global__ __launch_bounds__(256) void gemm_bf16(
    const TA* __restrict__ A, const float* __restrict__ W,
    const float* __restrict__ g, const float* __restrict__ bias,
    const TRES* __restrict__ Res, TOUT* __restrict__ Out,
    int Nn, int Kk){
  __shared__ short As[64][40];
  __shared__ short Bs[64][40];
  int bm = blockIdx.y*64, bn = blockIdx.x*64;
  int tid = threadIdx.x;
  int wave = tid >> 6, lane = tid & 63, quad = lane >> 4, l16 = lane & 15;
  f32x4 acc[4];
#pragma unroll
  for(int i=0;i<4;i++) acc[i] = (f32x4){0.f,0.f,0.f,0.f};
  int ar = tid >> 2, ac = (tid & 3) * 8;
  const TA*    Ap = A + (size_t)(bm + ar)*Kk + ac;
  const float* Wp = W + (size_t)(bn + ar)*Kk + ac;
  for(int k0=0; k0<Kk; k0+=32){
    *(bf16x8*)&As[ar][ac] = ld8cvt(Ap + k0);
    *(bf16x8*)&Bs[ar][ac] = ld8cvt(Wp + k0);
    __syncthreads();
    bf16x8 a = *(const bf16x8*)&As[wave*16 + l16][quad*8];
#pragma unroll
    for(int ct=0; ct<4; ct++){
      bf16x8 bb = *(const bf16x8*)&Bs[ct*16 + l16][quad*8];
      acc[ct] = __builtin_amdgcn_mfma_f32_16x16x32_bf16(a, bb, acc[ct], 0, 0, 0);
    }
    __syncthreads();
  }
#pragma unroll
  for(int ct=0; ct<4; ct++){
    int col = bn + ct*16 + l16;
    float gs = 0.f, bs_ = 0.f;
    if(HAS_BN){ gs = g[col] * BN_SCALE_F; bs_ = bias[col]; }
#pragma unroll
    for(int r2=0;r2<4;r2++){
      int row = bm + wave*16 + quad*4 + r2;
      float v = acc[ct][r2];
      if(HAS_BN) v = v*gs + bs_;
      if(HAS_RES) v += rdval(Res + (size_t)row*Nn + col);
      if(HAS_GELU) v = gelu_f(v);
      wrval(Out + (size_t)row*Nn + col, v);
    }
  }
}

// ---------------- f2 [B,S,C] bf16 -> x_out [B,C,S] f32 ---------------------
__global__ __launch_bounds__(256) void transpose_f(const short* __restrict__ f2, float* __restrict__ out1){
  __shared__ short tile[32][33];
  int b = blockIdx.z;
  int s0 = blockIdx.x*32, c0 = blockIdx.y*32;
  int tx = threadIdx.x & 31, ty = threadIdx.x >> 5;
#pragma unroll
  for(int i=0;i<32;i+=8)
    tile[ty+i][tx] = f2[((size_t)b*Sc + (s0+ty+i))*COUTc + c0+tx];
  __syncthreads();
#pragma unroll
  for(int i=0;i<32;i+=8)
    out1[((size_t)b*COUTc + (c0+ty+i))*Sc + s0+tx] = b2f(tile[tx][ty+i]);
}

// ------- Local2Former attention: block per (b,m); kv packed [row,512] ------
__global__ __launch_bounds__(256) void l2f_attn(
    const short* __restrict__ qb, const short* __restrict__ kv,
    short* __restrict__ ao){
  int blk = blockIdx.x; int b = blk / Mc; int m = blk % Mc;
  int tid = threadIdx.x;
  __shared__ float qs[TCHc];
  __shared__ float aw[Sc];
  __shared__ float red[8];
  qs[tid] = b2f(qb[(size_t)(b*Mc+m)*TCHc + tid]);
  __syncthreads();
  float sc[4];
#pragma unroll
  for(int jj=0;jj<4;jj++){
    int j = tid + 256*jj;
    const short* kp = kv + ((size_t)b*Sc + j)*512;
    float a = 0.f;
    for(int c=0;c<TCHc;c+=8){
      bf16x8 v8 = *(const bf16x8*)(kp + c);
#pragma unroll
      for(int i=0;i<8;i++) a += b2f(v8[i]) * qs[c+i];
    }
    sc[jj] = a * 0.0625f;   // TCH^-0.5
  }
  float mx = fmaxf(fmaxf(sc[0],sc[1]), fmaxf(sc[2],sc[3]));
#pragma unroll
  for(int off=32; off>0; off>>=1) mx = fmaxf(mx, __shfl_xor(mx, off));
  if((tid&63)==0) red[tid>>6] = mx;
  __syncthreads();
  mx = fmaxf(fmaxf(red[0],red[1]), fmaxf(red[2],red[3]));
  float se = 0.f;
#pragma unroll
  for(int jj=0;jj<4;jj++){
    float e = expf(sc[jj] - mx);
    aw[tid + 256*jj] = e;
    se += e;
  }
#pragma unroll
  for(int off=32; off>0; off>>=1) se += __shfl_xor(se, off);
  if((tid&63)==0) red[4 + (tid>>6)] = se;
  __syncthreads();
  se = red[4]+red[5]+red[6]+red[7];
  float inv = 1.f/se;
#pragma unroll
  for(int jj=0;jj<4;jj++) aw[tid + 256*jj] *= inv;
  __syncthreads();
  float acc = 0.f;
  const short* vp = kv + (size_t)b*Sc*512 + 256 + tid;
  for(int j=0;j<Sc;j++) acc += aw[j] * b2f(vp[(size_t)j*512]);
  ao[(size_t)(b*Mc+m)*TCHc + tid] = f2b(acc);
}

// ---------------- Former MHA: block per (b,h,m), 64 threads ----------------
__global__ __launch_bounds__(64) void former_attn(const short* __restrict__ qkv, short* __restrict__ oa){
  int blk = blockIdx.x;
  int m = blk % Mc; int bh = blk / Mc; int h = bh % Hc; int b = bh / Hc;
  int lane = threadIdx.x;
  __shared__ float qs[HDc];
  __shared__ float aw2[32];
  const short* base = qkv + (size_t)(b*Mc)*(3*TCHc);
  qs[lane] = b2f(base[(size_t)m*3*TCHc + h*HDc + lane]);
  __syncthreads();
  int j = lane & 31;
  const short* kp = base + (size_t)j*3*TCHc + TCHc + h*HDc;
  float s = 0.f;
  for(int d=0; d<HDc; d+=8){
    bf16x8 v8 = *(const bf16x8*)(kp + d);
#pragma unroll
    for(int i=0;i<8;i++) s += b2f(v8[i]) * qs[d+i];
  }
  s *= 0.125f;  // HD^-0.5
  float mx = s;
#pragma unroll
  for(int off=16; off>0; off>>=1) mx = fmaxf(mx, __shfl_xor(mx, off, 32));
  float e = expf(s - mx);
  float se = e;
#pragma unroll
  for(int off=16; off>0; off>>=1) se += __shfl_xor(se, off, 32);
  if(lane < 32) aw2[lane] = e / se;
  __syncthreads();
  float acc = 0.f;
  const short* vp = base + 2*TCHc + h*HDc + lane;
  for(int jj=0; jj<32; jj++) acc += aw2[jj] * b2f(vp[(size_t)jj*3*TCHc]);
  oa[(size_t)(b*Mc+m)*TCHc + h*HDc + lane] = f2b(acc);
}

// ---------------- LayerNorm over 256: f32 in, bf16 out ---------------------
__global__ __launch_bounds__(64) void ln_kernel(const float* __restrict__ X, const float* __restrict__ g,
                                                const float* __restrict__ bb, short* __restrict__ O){
  int row = blockIdx.x, lane = threadIdx.x;
  const float* xp = X + (size_t)row*TCHc;
  float x[4];
#pragma unroll
  for(int j2=0;j2<4;j2++) x[j2] = xp[lane + 64*j2];
  float sm = x[0]+x[1]+x[2]+x[3];
#pragma unroll
  for(int off=32; off>0; off>>=1) sm += __shfl_xor(sm, off);
  float mu = sm * (1.f/256.f);
  float vs = 0.f;
#pragma unroll
  for(int j2=0;j2<4;j2++){ float d = x[j2]-mu; vs += d*d; }
#pragma unroll
  for(int off=32; off>0; off>>=1) vs += __shfl_xor(vs, off);
  float var = vs * (1.f/256.f);
  float rstd = 1.f / sqrtf(var + 1e-5f);
#pragma unroll
  for(int j2=0;j2<4;j2++){
    int c = lane + 64*j2;
    float o = (x[j2]-mu)*rstd*g[c] + bb[c];
    O[(size_t)row*TCHc + c] = f2b(o);
  }
}

extern "C" void kernel_launch(void* const* d_in, const int* in_sizes, int n_in,
                              void* d_out, int out_size, void* d_ws, size_t ws_size,
                              hipStream_t stream){
  const float* xyz  = (const float*)d_in[0];
  const float* x    = (const float*)d_in[1];
  const float* t_in = (const float*)d_in[2];
  const int*   far0 = (const int*)d_in[3];
  const float* Wproj=(const float*)d_in[4];  const float* gproj=(const float*)d_in[5];  const float* bproj=(const float*)d_in[6];
  const float* Wl1 = (const float*)d_in[7];  const float* gl1 = (const float*)d_in[8];  const float* bl1 = (const float*)d_in[9];
  const float* Wl2 = (const float*)d_in[10]; const float* gl2 = (const float*)d_in[11]; const float* bl2 = (const float*)d_in[12];
  const float* Wc1 = (const float*)d_in[13]; const float* gc1 = (const float*)d_in[14]; const float* bc1 = (const float*)d_in[15];
  const float* Wc2 = (const float*)d_in[16]; const float* gc2 = (const float*)d_in[17]; const float* bc2 = (const float*)d_in[18];
  const float* Wq  = (const float*)d_in[19]; const float* Wk  = (const float*)d_in[20]; const float* Wv  = (const float*)d_in[21];
  const float* Wo  = (const float*)d_in[22];
  const float* ln1g= (const float*)d_in[23]; const float* ln1b= (const float*)d_in[24];
  const float* Wqkv= (const float*)d_in[25]; const float* Wao = (const float*)d_in[26];
  const float* ln2g= (const float*)d_in[27]; const float* ln2b= (const float*)d_in[28];
  const float* Wf1 = (const float*)d_in[29]; const float* Wf2 = (const float*)d_in[30];

  char* wsb = (char*)d_ws;
  size_t off = 0;
  auto alloc = [&](size_t bytes)->void*{ void* p = wsb + off; off += (bytes + 255) & ~(size_t)255; return p; };
  int*   fps_i = (int*)alloc((size_t)Bc*Sc*4);
  float* ddb   = (float*)alloc((size_t)Bc*Nc*4);
  int*   knn   = (int*)alloc((size_t)Bc*Sc*Kc*4);
  short* xT    = (short*)alloc((size_t)Bc*Nc*CINc*2);
  short* wbf   = (short*)alloc((size_t)(COUTc*CINc + 4*COUTc*COUTc + 2*TCHc*COUTc)*2);
  short* fbuf  = (short*)alloc((size_t)Bc*Sc*COUTc*2);
  short* rcbuf = (short*)alloc((size_t)Bc*Sc*COUTc*2);
  short* f2buf = (short*)alloc((size_t)Bc*Sc*COUTc*2);
  short* kvbuf = (short*)alloc((size_t)Bc*Sc*512*2);
  short* qbuf  = (short*)alloc((size_t)Bc*Mc*TCHc*2);
  short* a1out = (short*)alloc((size_t)Bc*Mc*TCHc*2);
  float* t1buf = (float*)alloc((size_t)Bc*Mc*TCHc*4);
  short* hnbuf = (short*)alloc((size_t)Bc*Mc*TCHc*2);
  short* qkvb  = (short*)alloc((size_t)Bc*Mc*3*TCHc*2);
  short* a2out = (short*)alloc((size_t)Bc*Mc*TCHc*2);
  float* t2buf = (float*)alloc((size_t)Bc*Mc*TCHc*4);
  short* hn2buf= (short*)alloc((size_t)Bc*Mc*TCHc*2);
  short* g1buf = (short*)alloc((size_t)Bc*Mc*2*TCHc*2);
  size_t full_bytes  = (size_t)Bc*MBAT*COUTc*2;   // ~96 MB
  size_t batch_bytes = (size_t)MBAT*COUTc*2;      // ~12 MB
  bool batched = (off + 2*(full_bytes + 256) <= ws_size);
  short* hbuf = (short*)alloc(batched ? full_bytes : batch_bytes);
  short* rbuf = (short*)alloc(batched ? full_bytes : batch_bytes);
  if(off > ws_size) return;  // insufficient workspace; fail visibly

  short* wproj_bf = wbf;
  short* wl1_bf   = wproj_bf + COUTc*CINc;
  short* wl2_bf   = wl1_bf + COUTc*COUTc;
  short* wc1_bf   = wl2_bf + COUTc*COUTc;
  short* wc2_bf   = wc1_bf + COUTc*COUTc;
  short* wkv_bf   = wc2_bf + COUTc*COUTc;   // [512,256]: Wk rows then Wv rows

  float* out0 = (float*)d_out;
  float* out1 = out0 + (size_t)Bc*Sc*3;
  float* out2 = out1 + (size_t)Bc*COUTc*Sc;

  // --- prep: fps + transpose_x + weight cvt + dd in one launch ---
  prep_kernel<<<PREP_TOTAL, 256, 0, stream>>>(xyz, far0, fps_i, x, xT,
                                              Wproj, Wl1, Wl2, Wc1, Wc2, Wk, Wv, wbf, ddb);
  knn_kernel<<<Bc*Sc, 256, 0, stream>>>(xyz, fps_i, ddb, knn, out0);
  // --- Local ---
  if(batched){
    proj128<<<dim3(COUTc/128, (Bc*MBAT)/128), 256, 0, stream>>>(xT, knn, fps_i, wproj_bf, gproj, bproj, hbuf, 0);
    gemm128<1,1,0,short><<<dim3(COUTc/128, (Bc*MBAT)/128), 256, 0, stream>>>(hbuf, wl1_bf, gl1, bl1, (const short*)nullptr, rbuf, COUTc, COUTc);
    l2max96<<<dim3(COUTc/128, (Bc*MBAT)/96), 256, 0, stream>>>(rbuf, wl2_bf, gl2, bl2, hbuf, fbuf, 0);
  } else {
    for(int b=0; b<Bc; b++){
      proj128<<<dim3(COUTc/128, MBAT/128), 256, 0, stream>>>(xT, knn, fps_i, wproj_bf, gproj, bproj, hbuf, b*MBAT);
      gemm128<1,1,0,short><<<dim3(COUTc/128, MBAT/128), 256, 0, stream>>>(hbuf, wl1_bf, gl1, bl1, (const short*)nullptr, rbuf, COUTc, COUTc);
      l2max96<<<dim3(COUTc/128, MBAT/96), 256, 0, stream>>>(rbuf, wl2_bf, gl2, bl2, hbuf, fbuf, b*MBAT);
    }
  }
  // --- Channel ---
  gemm64d<1,1,0,short,short><<<dim3(COUTc/64, (Bc*Sc)/64), 256, 0, stream>>>(fbuf, wc1_bf, gc1, bc1, (const short*)nullptr, rcbuf, COUTc, COUTc);
  gemm64d<1,1,1,short,short><<<dim3(COUTc/64, (Bc*Sc)/64), 256, 0, stream>>>(rcbuf, wc2_bf, gc2, bc2, fbuf, f2buf, COUTc, COUTc);
  transpose_f<<<dim3(Sc/32, COUTc/32, Bc), 256, 0, stream>>>(f2buf, out1);
  // --- Local2Former ---
  gemm_bf16<float,short,short,0,0,0><<<dim3(TCHc/64, (Bc*Mc)/64), 256, 0, stream>>>(t_in, Wq, nullptr, nullptr, (const short*)nullptr, qbuf, TCHc, TCHc);
  gemm64d<0,0,0,short,short><<<dim3(512/64, (Bc*Sc)/64), 256, 0, stream>>>(f2buf, wkv_bf, nullptr, nullptr, (const short*)nullptr, kvbuf, 512, COUTc);
  l2f_attn<<<Bc*Mc, 256, 0, stream>>>(qbuf, kvbuf, a1out);
  gemm_bf16<short,float,float,0,0,1><<<dim3(TCHc/64, (Bc*Mc)/64), 256, 0, stream>>>(a1out, Wo, nullptr, nullptr, t_in, t1buf, TCHc, TCHc);
  // --- Former ---
  ln_kernel<<<Bc*Mc, 64, 0, stream>>>(t1buf, ln1g, ln1b, hnbuf);
  gemm_bf16<short,short,short,0,0,0><<<dim3((3*TCHc)/64, (Bc*Mc)/64), 256, 0, stream>>>(hnbuf, Wqkv, nullptr, nullptr, (const short*)nullptr, qkvb, 3*TCHc, TCHc);
  former_attn<<<Bc*Hc*Mc, 64, 0, stream>>>(qkvb, a2out);
  gemm_bf16<short,float,float,0,0,1><<<dim3(TCHc/64, (Bc*Mc)/64), 256, 0, stream>>>(a2out, Wao, nullptr, nullptr, t1buf, t2buf, TCHc, TCHc);
  ln_kernel<<<Bc*Mc, 64, 0, stream>>>(t2buf, ln2g, ln2b, hn2buf);
  gemm_bf16<short,short,short,0,1,0><<<dim3((2*TCHc)/64, (Bc*Mc)/64), 256, 0, stream>>>(hn2buf, Wf1, nullptr, nullptr, (const short*)nullptr, g1buf, 2*TCHc, TCHc);
  gemm_bf16<short,float,float,0,0,1><<<dim3(TCHc/64, (Bc*Mc)/64), 256, 0, stream>>>(g1buf, Wf2, nullptr, nullptr, t2buf, out2, TCHc, 2*TCHc);
}

// Round 13
// 1210.987 us; speedup vs baseline: 1.2070x; 1.2070x over previous
//
#include <hip/hip_runtime.h>
#include <math.h>

#define Bc 8
#define Nc 4096
#define CINc 128
#define COUTc 256
#define Sc 1024
#define Kc 24
#define TCHc 256
#define Mc 32
#define Hc 4
#define HDc 64
#define MBAT (Sc*Kc)      // rows per batch in Local stage: 24576

#define BN_SCALE_F 0.9999950000374997f

typedef __attribute__((ext_vector_type(8))) short bf16x8;
typedef __attribute__((ext_vector_type(4))) float f32x4;

__device__ __forceinline__ float b2f(short s){
  unsigned int u = ((unsigned int)(unsigned short)s) << 16;
  union { unsigned int u; float f; } c; c.u = u; return c.f;
}
__device__ __forceinline__ short f2b(float f){
  union { unsigned int u; float f; } c; c.f = f;
  unsigned int u = c.u;
  unsigned int r = (u + 0x7fffu + ((u >> 16) & 1u)) >> 16;
  return (short)(r & 0xffffu);
}
__device__ __forceinline__ float gelu_f(float v){
  return 0.5f * v * (1.f + erff(v * 0.7071067811865475f));
}
__device__ __forceinline__ float rdval(const float* p){ return *p; }
__device__ __forceinline__ float rdval(const short* p){ return b2f(*p); }
__device__ __forceinline__ void wrval(float* p, float v){ *p = v; }
__device__ __forceinline__ void wrval(short* p, float v){ *p = f2b(v); }

// async global->LDS, 16B per lane (dest follows lane order: base + lane*16B)
__device__ __forceinline__ void gl_lds16(const short* g, short* l){
  __builtin_amdgcn_global_load_lds(
     (const __attribute__((address_space(1))) void*)g,
     (__attribute__((address_space(3))) void*)l, 16, 0, 0);
}

template<int CTRL>
__device__ __forceinline__ double dpp_max_f64(double v){
  long long x = __double_as_longlong(v);
  int lo = (int)(unsigned int)(x & 0xFFFFFFFFLL);
  int hi = (int)(unsigned int)((unsigned long long)x >> 32);
  int plo = __builtin_amdgcn_update_dpp(lo, lo, CTRL, 0xF, 0xF, false);
  int phi = __builtin_amdgcn_update_dpp(hi, hi, CTRL, 0xF, 0xF, false);
  double p = __longlong_as_double((long long)(((unsigned long long)(unsigned int)phi << 32)
                                              | (unsigned int)plo));
  return fmax(v, p);
}
template<int CTRL>
__device__ __forceinline__ float dpp_min_f32(float v){
  int x = __float_as_int(v);
  int p = __builtin_amdgcn_update_dpp(x, x, CTRL, 0xF, 0xF, false);
  return fminf(v, __int_as_float(p));
}
template<int CTRL>
__device__ __forceinline__ unsigned dpp_min_u32(unsigned v){
  int p = __builtin_amdgcn_update_dpp((int)v, (int)v, CTRL, 0xF, 0xF, false);
  unsigned pu = (unsigned)p;
  return v < pu ? v : pu;
}

// ---------------- prep mega-kernel (256 thr): fps(8) | tx(4096) | cvt(64) | dd(128)
#define PREP_FPS 8
#define PREP_TX 4096
#define PREP_CVT 64
#define PREP_DD 128
#define PREP_TOTAL (PREP_FPS+PREP_TX+PREP_CVT+PREP_DD)

__global__ __launch_bounds__(256) void prep_kernel(
    const float* __restrict__ xyz, const int* __restrict__ far0, int* __restrict__ fps_idx,
    const float* __restrict__ x, short* __restrict__ xT,
    const float* __restrict__ Wproj, const float* __restrict__ Wl1, const float* __restrict__ Wl2,
    const float* __restrict__ Wc1, const float* __restrict__ Wc2,
    const float* __restrict__ Wk, const float* __restrict__ Wv,
    const float* __restrict__ Wq, const float* __restrict__ Wo,
    const float* __restrict__ Wqkv, const float* __restrict__ Wao,
    const float* __restrict__ Wf1, const float* __restrict__ Wf2,
    const float* __restrict__ t_in,
    short* __restrict__ wbf, float* __restrict__ dd){
  __shared__ double smem[6176];   // 49408 B: fps sx/sy/sz (48KB) + pwave; reused by others
  int bid = blockIdx.x, tid = threadIdx.x;
  if(bid < PREP_FPS){
    // ---- FPS (round-6/10 proven logic, 256 thr, 16 pts/thread) ----
    int b = bid;
    float* sx = (float*)smem;
    float* sy = sx + Nc;
    float* sz = sy + Nc;
    double* pwave = smem + (Nc*12)/8;   // [2][4]
    const float* xb = xyz + (size_t)b*Nc*3;
    for(int i=tid; i<Nc; i+=256){
      const float* p = xb + i*3;
      sx[i]=p[0]; sy[i]=p[1]; sz[i]=p[2];
    }
    __syncthreads();
    float px[16], py[16], pz[16], dmin[16];
    unsigned int lokey[16];
#pragma unroll
    for(int j=0;j<16;j++){
      int n = tid + 256*j;
      px[j]=sx[n]; py[j]=sy[n]; pz[j]=sz[n];
      dmin[j]=1e10f;
      lokey[j]=(unsigned int)((Nc-1) - n);
    }
    int winner = far0[b] & (Nc-1);
    int* out = fps_idx + b*Sc;
    for(int it=0; it<Sc; it++){
      if(tid==0) out[it] = winner;
      float cx=sx[winner], cy=sy[winner], cz=sz[winner];
      double key[16];
#pragma unroll
      for(int j=0;j<16;j++){
        float dx = __fsub_rn(px[j], cx);
        float dy = __fsub_rn(py[j], cy);
        float dz = __fsub_rn(pz[j], cz);
        float d = __fadd_rn(__fadd_rn(__fmul_rn(dx,dx), __fmul_rn(dy,dy)), __fmul_rn(dz,dz));
        dmin[j] = fminf(dmin[j], d);
        unsigned long long k = (((unsigned long long)__float_as_uint(dmin[j])) << 32) | lokey[j];
        key[j] = __longlong_as_double((long long)k);
      }
#pragma unroll
      for(int st=8; st>0; st>>=1)
#pragma unroll
        for(int j=0;j<st;j++) key[j] = fmax(key[j], key[j+st]);
      double kv = key[0];
      kv = dpp_max_f64<0x111>(kv);
      kv = dpp_max_f64<0x112>(kv);
      kv = dpp_max_f64<0x114>(kv);
      kv = dpp_max_f64<0x118>(kv);
      kv = dpp_max_f64<0x142>(kv);
      kv = dpp_max_f64<0x143>(kv);
      int p = it & 1;
      if((tid & 63) == 63) pwave[p*4 + (tid>>6)] = kv;
      __syncthreads();
      double k0 = pwave[p*4+0], k1 = pwave[p*4+1], k2 = pwave[p*4+2], k3 = pwave[p*4+3];
      double kb = fmax(fmax(k0,k1), fmax(k2,k3));
      unsigned long long kbits = (unsigned long long)__double_as_longlong(kb);
      winner = (Nc-1) - (int)(kbits & 0xFFFFFFFFULL);
    }
  } else if(bid < PREP_FPS+PREP_TX){
    int t = bid - PREP_FPS;
    int b = t >> 9;
    int rem = t & 511;
    int n0 = (rem & 127) * 32;
    int c0 = (rem >> 7) * 32;
    short (*tile)[33] = (short(*)[33])smem;
    int tx = tid & 31, ty = tid >> 5;
#pragma unroll
    for(int i=0;i<32;i+=8)
      tile[ty+i][tx] = f2b(x[((size_t)b*CINc + (c0+ty+i))*Nc + n0+tx]);
    __syncthreads();
#pragma unroll
    for(int i=0;i<32;i+=8)
      xT[((size_t)b*Nc + (n0+ty+i))*CINc + c0+tx] = tile[tx][ty+i];
  } else if(bid < PREP_FPS+PREP_TX+PREP_CVT){
    int gid = (bid - PREP_FPS - PREP_TX)*256 + tid;
    const int stride = PREP_CVT*256;
    short* p = wbf;
    for(int i=gid; i<COUTc*CINc; i+=stride) p[i] = f2b(Wproj[i]);
    p += COUTc*CINc;
    for(int i=gid; i<COUTc*COUTc; i+=stride) p[i] = f2b(Wl1[i]);
    p += COUTc*COUTc;
    for(int i=gid; i<COUTc*COUTc; i+=stride) p[i] = f2b(Wl2[i]);
    p += COUTc*COUTc;
    for(int i=gid; i<COUTc*COUTc; i+=stride) p[i] = f2b(Wc1[i]);
    p += COUTc*COUTc;
    for(int i=gid; i<COUTc*COUTc; i+=stride) p[i] = f2b(Wc2[i]);
    p += COUTc*COUTc;
    for(int i=gid; i<TCHc*COUTc; i+=stride) p[i] = f2b(Wk[i]);
    p += TCHc*COUTc;
    for(int i=gid; i<TCHc*COUTc; i+=stride) p[i] = f2b(Wv[i]);
    p += TCHc*COUTc;
    for(int i=gid; i<TCHc*TCHc; i+=stride) p[i] = f2b(Wq[i]);
    p += TCHc*TCHc;
    for(int i=gid; i<TCHc*TCHc; i+=stride) p[i] = f2b(Wo[i]);
    p += TCHc*TCHc;
    for(int i=gid; i<3*TCHc*TCHc; i+=stride) p[i] = f2b(Wqkv[i]);
    p += 3*TCHc*TCHc;
    for(int i=gid; i<TCHc*TCHc; i+=stride) p[i] = f2b(Wao[i]);
    p += TCHc*TCHc;
    for(int i=gid; i<2*TCHc*TCHc; i+=stride) p[i] = f2b(Wf1[i]);
    p += 2*TCHc*TCHc;
    for(int i=gid; i<2*TCHc*TCHc; i+=stride) p[i] = f2b(Wf2[i]);
    p += 2*TCHc*TCHc;
    for(int i=gid; i<Bc*Mc*TCHc; i+=stride) p[i] = f2b(t_in[i]);
  } else {
    int i = (bid - PREP_FPS - PREP_TX - PREP_CVT)*256 + tid;
    const float* p = xyz + (size_t)i*3;
    float xx=p[0], yy=p[1], zz=p[2];
    dd[i] = __fadd_rn(__fadd_rn(__fmul_rn(xx,xx),__fmul_rn(yy,yy)),__fmul_rn(zz,zz));
  }
}

// ---------------- KNN: block per (b,s); DPP-based argmin rounds ------------
__global__ __launch_bounds__(256) void knn_kernel(const float* __restrict__ xyz,
                                                  const int* __restrict__ fps_idx,
                                                  const float* __restrict__ dd,
                                                  int* __restrict__ knn_idx,
                                                  float* __restrict__ out0){
  int bs = blockIdx.x, tid = threadIdx.x;
  int b = bs >> 10;
  __shared__ float pv[4]; __shared__ int pi[4];
  int qn = fps_idx[bs] & (Nc-1);
  const float* q = xyz + ((size_t)b*Nc + qn)*3;
  float sx = q[0], sy = q[1], sz = q[2];
  if(tid < 3) out0[bs*3 + tid] = q[tid];
  float ss = __fadd_rn(__fadd_rn(__fmul_rn(sx,sx),__fmul_rn(sy,sy)),__fmul_rn(sz,sz));
  const float* xb = xyz + (size_t)b*Nc*3;
  const float* db = dd + b*Nc;
  float dv[16];
#pragma unroll
  for(int j=0;j<16;j++){
    int n = tid + 256*j;
    float xx=xb[n*3], yy=xb[n*3+1], zz=xb[n*3+2];
    float e = __fmul_rn(sx,xx);
    e = __fadd_rn(e, __fmul_rn(sy,yy));
    e = __fadd_rn(e, __fmul_rn(sz,zz));
    dv[j] = __fadd_rn(__fadd_rn(__fmul_rn(-2.f,e), ss), db[n]);
  }
  int* ob = knn_idx + (size_t)bs*Kc;
  for(int k=0;k<Kc;k++){
    float bvv = dv[0];
#pragma unroll
    for(int j=1;j<16;j++) bvv = fminf(bvv, dv[j]);
    bvv = dpp_min_f32<0x111>(bvv);
    bvv = dpp_min_f32<0x112>(bvv);
    bvv = dpp_min_f32<0x114>(bvv);
    bvv = dpp_min_f32<0x118>(bvv);
    bvv = dpp_min_f32<0x142>(bvv);
    bvv = dpp_min_f32<0x143>(bvv);
    if((tid&63)==63) pv[tid>>6] = bvv;
    __syncthreads();
    float vmin = fminf(fminf(pv[0],pv[1]), fminf(pv[2],pv[3]));
    unsigned bi = 0xFFFFFFFFu;
#pragma unroll
    for(int j=0;j<16;j++){
      unsigned n = (unsigned)(tid + 256*j);
      if(dv[j]==vmin && n < bi) bi = n;
    }
    bi = dpp_min_u32<0x111>(bi);
    bi = dpp_min_u32<0x112>(bi);
    bi = dpp_min_u32<0x114>(bi);
    bi = dpp_min_u32<0x118>(bi);
    bi = dpp_min_u32<0x142>(bi);
    bi = dpp_min_u32<0x143>(bi);
    if((tid&63)==63) pi[tid>>6] = (int)bi;
    __syncthreads();
    unsigned i0=(unsigned)pi[0], i1=(unsigned)pi[1], i2=(unsigned)pi[2], i3=(unsigned)pi[3];
    unsigned m01 = i0<i1?i0:i1, m23 = i2<i3?i2:i3;
    unsigned win = m01<m23?m01:m23;
    if(tid==0) ob[k] = (int)(win & (Nc-1));
#pragma unroll
    for(int j=0;j<16;j++) if((int)win == tid + 256*j) dv[j] = 3.4e38f;
  }
}

// ---------------- 128x128 MFMA GEMM, A/W bf16 ------------------------------
template<int HAS_BN, int HAS_GELU, int HAS_RES, typename TRES>
__global__ __launch_bounds__(256) void gemm128(
    const short* __restrict__ A, const short* __restrict__ W,
    const float* __restrict__ g, const float* __restrict__ bias,
    const TRES* __restrict__ Res, short* __restrict__ Out,
    int Nn, int Kk){
  __shared__ short As[128*32];
  __shared__ short Bs[128*32];
  int bm = blockIdx.y*128, bn = blockIdx.x*128;
  int tid = threadIdx.x;
  int wave = tid>>6, lane = tid&63, quad = lane>>4, l16 = lane&15;
  int wr = (wave>>1)*64, wc = (wave&1)*64;
  f32x4 acc[4][4];
#pragma unroll
  for(int i=0;i<4;i++)
#pragma unroll
    for(int j=0;j<4;j++) acc[i][j] = (f32x4){0.f,0.f,0.f,0.f};
  int sr = tid>>2, scc = (tid&3)*8;
  const short* Ap = A + (size_t)(bm+sr)*Kk + scc;
  const short* Wp = W + (size_t)(bn+sr)*Kk + scc;
  for(int k0=0; k0<Kk; k0+=32){
    gl_lds16(Ap + k0,                    As + tid*8);
    gl_lds16(Ap + k0 + (size_t)64*Kk,    As + 2048 + tid*8);
    gl_lds16(Wp + k0,                    Bs + tid*8);
    gl_lds16(Wp + k0 + (size_t)64*Kk,    Bs + 2048 + tid*8);
    __syncthreads();
    bf16x8 af[4], bfr[4];
#pragma unroll
    for(int mt=0; mt<4; mt++) af[mt]  = *(const bf16x8*)&As[(wr+mt*16+l16)*32 + quad*8];
#pragma unroll
    for(int nt=0; nt<4; nt++) bfr[nt] = *(const bf16x8*)&Bs[(wc+nt*16+l16)*32 + quad*8];
#pragma unroll
    for(int mt=0; mt<4; mt++)
#pragma unroll
      for(int nt=0; nt<4; nt++)
        acc[mt][nt] = __builtin_amdgcn_mfma_f32_16x16x32_bf16(af[mt], bfr[nt], acc[mt][nt], 0, 0, 0);
    __syncthreads();
  }
#pragma unroll
  for(int nt=0; nt<4; nt++){
    int col = bn + wc + nt*16 + l16;
    float gs = 0.f, bs_ = 0.f;
    if(HAS_BN){ gs = g[col] * BN_SCALE_F; bs_ = bias[col]; }
#pragma unroll
    for(int mt=0; mt<4; mt++){
#pragma unroll
      for(int r2=0;r2<4;r2++){
        int row = bm + wr + mt*16 + quad*4 + r2;
        float v = acc[mt][nt][r2];
        if(HAS_BN) v = v*gs + bs_;
        if(HAS_RES) v += rdval(Res + (size_t)row*Nn + col);
        if(HAS_GELU) v = gelu_f(v);
        Out[(size_t)row*Nn + col] = f2b(v);
      }
    }
  }
}

// ------- proj 128x128: gathered edge A, W via DMA; rows offset by R0 -------
__global__ __launch_bounds__(256) void proj128(
    const short* __restrict__ xT, const int* __restrict__ knn_idx, const int* __restrict__ fps_idx,
    const short* __restrict__ W, const float* __restrict__ g, const float* __restrict__ bias,
    short* __restrict__ Out, int R0){
  __shared__ short As[128*32];
  __shared__ short Bs[128*32];
  int bm = blockIdx.y*128, bn = blockIdx.x*128;
  int tid = threadIdx.x;
  int wave = tid>>6, lane = tid&63, quad = lane>>4, l16 = lane&15;
  int wr = (wave>>1)*64, wc = (wave&1)*64;
  f32x4 acc[4][4];
#pragma unroll
  for(int i=0;i<4;i++)
#pragma unroll
    for(int j=0;j<4;j++) acc[i][j] = (f32x4){0.f,0.f,0.f,0.f};
  int sr = tid>>2, scc = (tid&3)*8;
  int Rg0 = R0 + bm + sr, Rg1 = Rg0 + 64;
  int b0 = Rg0 / (Sc*Kc), b1 = Rg1 / (Sc*Kc);
  int nk0 = knn_idx[Rg0] & (Nc-1), nk1 = knn_idx[Rg1] & (Nc-1);
  int nc0 = fps_idx[Rg0 / Kc] & (Nc-1), nc1 = fps_idx[Rg1 / Kc] & (Nc-1);
  const short* pk0 = xT + ((size_t)b0*Nc + nk0)*CINc + scc;
  const short* pc0 = xT + ((size_t)b0*Nc + nc0)*CINc + scc;
  const short* pk1 = xT + ((size_t)b1*Nc + nk1)*CINc + scc;
  const short* pc1 = xT + ((size_t)b1*Nc + nc1)*CINc + scc;
  const short* Wp  = W + (size_t)(bn+sr)*CINc + scc;
  for(int k0=0; k0<CINc; k0+=32){
    gl_lds16(Wp + k0,                      Bs + tid*8);
    gl_lds16(Wp + k0 + (size_t)64*CINc,    Bs + 2048 + tid*8);
    bf16x8 vk = *(const bf16x8*)(pk0 + k0);
    bf16x8 vc = *(const bf16x8*)(pc0 + k0);
    bf16x8 e0, e1;
#pragma unroll
    for(int i=0;i<8;i++) e0[i] = f2b(__fsub_rn(b2f(vk[i]), b2f(vc[i])));
    vk = *(const bf16x8*)(pk1 + k0);
    vc = *(const bf16x8*)(pc1 + k0);
#pragma unroll
    for(int i=0;i<8;i++) e1[i] = f2b(__fsub_rn(b2f(vk[i]), b2f(vc[i])));
    *(bf16x8*)&As[tid*8] = e0;
    *(bf16x8*)&As[2048 + tid*8] = e1;
    __syncthreads();
    bf16x8 af[4], bfr[4];
#pragma unroll
    for(int mt=0; mt<4; mt++) af[mt]  = *(const bf16x8*)&As[(wr+mt*16+l16)*32 + quad*8];
#pragma unroll
    for(int nt=0; nt<4; nt++) bfr[nt] = *(const bf16x8*)&Bs[(wc+nt*16+l16)*32 + quad*8];
#pragma unroll
    for(int mt=0; mt<4; mt++)
#pragma unroll
      for(int nt=0; nt<4; nt++)
        acc[mt][nt] = __builtin_amdgcn_mfma_f32_16x16x32_bf16(af[mt], bfr[nt], acc[mt][nt], 0, 0, 0);
    __syncthreads();
  }
#pragma unroll
  for(int nt=0; nt<4; nt++){
    int col = bn + wc + nt*16 + l16;
    float gs = g[col] * BN_SCALE_F, bs_ = bias[col];
#pragma unroll
    for(int mt=0; mt<4; mt++){
#pragma unroll
      for(int r2=0;r2<4;r2++){
        int row = bm + wr + mt*16 + quad*4 + r2;
        float v = acc[mt][nt][r2]*gs + bs_;
        Out[(size_t)row*COUTc + col] = f2b(gelu_f(v));
      }
    }
  }
}

// -- l2 GEMM + residual + gelu + max over k (BM=48), A & W bf16 via DMA -----
__global__ __launch_bounds__(192) void gemm_l2max(
    const short* __restrict__ A, const short* __restrict__ W,
    const float* __restrict__ g, const float* __restrict__ bias,
    const short* __restrict__ Hres, short* __restrict__ Fout, int R0){
  __shared__ short As[48*32];
  __shared__ short Bs[64*32];
  __shared__ float sm[48][65];
  int bm = blockIdx.y*48, bn = blockIdx.x*64;
  int tid = threadIdx.x;
  int wave = tid >> 6, lane = tid & 63, quad = lane >> 4, l16 = lane & 15;
  f32x4 acc[4];
#pragma unroll
  for(int i=0;i<4;i++) acc[i] = (f32x4){0.f,0.f,0.f,0.f};
  const short* Ap  = A + (size_t)(bm + (tid>>2))*COUTc + (tid&3)*8;
  const short* Wp  = W + (size_t)(bn + (tid>>2))*COUTc + (tid&3)*8;
  const short* Wp2 = W + (size_t)(bn + 48 + (lane>>2))*COUTc + (lane&3)*8;
  for(int k0=0; k0<COUTc; k0+=32){
    gl_lds16(Ap + k0, As + tid*8);
    gl_lds16(Wp + k0, Bs + tid*8);
    if(wave==0) gl_lds16(Wp2 + k0, Bs + 1536 + lane*8);
    __syncthreads();
    bf16x8 a = *(const bf16x8*)&As[(wave*16 + l16)*32 + quad*8];
#pragma unroll
    for(int ct=0; ct<4; ct++){
      bf16x8 bb = *(const bf16x8*)&Bs[(ct*16 + l16)*32 + quad*8];
      acc[ct] = __builtin_amdgcn_mfma_f32_16x16x32_bf16(a, bb, acc[ct], 0, 0, 0);
    }
    __syncthreads();
  }
#pragma unroll
  for(int ct=0; ct<4; ct++){
    int col = bn + ct*16 + l16;
    float gs = g[col] * BN_SCALE_F, bs_ = bias[col];
#pragma unroll
    for(int r2=0;r2<4;r2++){
      int rl = wave*16 + quad*4 + r2;
      float v = acc[ct][r2]*gs + bs_;
      v += b2f(Hres[(size_t)(bm+rl)*COUTc + col]);
      sm[rl][ct*16 + l16] = gelu_f(v);
    }
  }
  __syncthreads();
  if(tid < 128){
    int gl = tid >> 6, col = tid & 63;
    float mx = -3.4e38f;
#pragma unroll
    for(int kk=0; kk<Kc; kk++) mx = fmaxf(mx, sm[gl*Kc + kk][col]);
    int gg = R0/Kc + blockIdx.y*2 + gl;   // global (b*Sc+s)
    Fout[(size_t)gg*COUTc + bn + col] = f2b(mx);
  }
}

// ------- 64x64 MFMA GEMM, A & W bf16, both staged via global_load_lds ------
template<int HAS_BN, int HAS_GELU, int HAS_RES, typename TRES, typename TOUT>
__global__ __launch_bounds__(256) void gemm64d(
    const short* __restrict__ A, const short* __restrict__ W,
    const float* __restrict__ g, const float* __restrict__ bias,
    const TRES* __restrict__ Res, TOUT* __restrict__ Out,
    int Nn, int Kk){
  __shared__ short As[64*32];
  __shared__ short Bs[64*32];
  int bm = blockIdx.y*64, bn = blockIdx.x*64;
  int tid = threadIdx.x;
  int wave = tid >> 6, lane = tid & 63, quad = lane >> 4, l16 = lane & 15;
  f32x4 acc[4];
#pragma unroll
  for(int i=0;i<4;i++) acc[i] = (f32x4){0.f,0.f,0.f,0.f};
  const short* Ap = A + (size_t)(bm + (tid>>2))*Kk + (tid&3)*8;
  const short* Wp = W + (size_t)(bn + (tid>>2))*Kk + (tid&3)*8;
  for(int k0=0; k0<Kk; k0+=32){
    gl_lds16(Ap + k0, As + tid*8);
    gl_lds16(Wp + k0, Bs + tid*8);
    __syncthreads();
    bf16x8 a = *(const bf16x8*)&As[(wave*16 + l16)*32 + quad*8];
#pragma unroll
    for(int ct=0; ct<4; ct++){
      bf16x8 bb = *(const bf16x8*)&Bs[(ct*16 + l16)*32 + quad*8];
      acc[ct] = __builtin_amdgcn_mfma_f32_16x16x32_bf16(a, bb, acc[ct], 0, 0, 0);
    }
    __syncthreads();
  }
#pragma unroll
  for(int ct=0; ct<4; ct++){
    int col = bn + ct*16 + l16;
    float gs = 0.f, bs_ = 0.f;
    if(HAS_BN){ gs = g[col] * BN_SCALE_F; bs_ = bias[col]; }
#pragma unroll
    for(int r2=0;r2<4;r2++){
      int row = bm + wave*16 + quad*4 + r2;
      float v = acc[ct][r2];
      if(HAS_BN) v = v*gs + bs_;
      if(HAS_RES) v += rdval(Res + (size_t)row*Nn + col);
      if(HAS_GELU) v = gelu_f(v);
      wrval(Out + (size_t)row*Nn + col, v);
    }
  }
}

// ---------------- f2 [B,S,C] bf16 -> x_out [B,C,S] f32 ---------------------
__global__ __launch_bounds__(256) void transpose_f(const short* __restrict__ f2, float* __restrict__ out1){
  __shared__ short tile[32][33];
  int b = blockIdx.z;
  int s0 = blockIdx.x*32, c0 = blockIdx.y*32;
  int tx = threadIdx.x & 31, ty = threadIdx.x >> 5;
#pragma unroll
  for(int i=0;i<32;i+=8)
    tile[ty+i][tx] = f2[((size_t)b*Sc + (s0+ty+i))*COUTc + c0+tx];
  __syncthreads();
#pragma unroll
  for(int i=0;i<32;i+=8)
    out1[((size_t)b*COUTc + (c0+ty+i))*Sc + s0+tx] = b2f(tile[tx][ty+i]);
}

// ------- Local2Former attention: block per (b,m); kv packed [row,512] ------
__global__ __launch_bounds__(256) void l2f_attn(
    const short* __restrict__ qb, const short* __restrict__ kv,
    short* __restrict__ ao){
  int blk = blockIdx.x; int b = blk / Mc; int m = blk % Mc;
  int tid = threadIdx.x;
  __shared__ float qs[TCHc];
  __shared__ float aw[Sc];
  __shared__ float red[8];
  qs[tid] = b2f(qb[(size_t)(b*Mc+m)*TCHc + tid]);
  __syncthreads();
  float sc[4];
#pragma unroll
  for(int jj=0;jj<4;jj++){
    int j = tid + 256*jj;
    const short* kp = kv + ((size_t)b*Sc + j)*512;
    float a = 0.f;
    for(int c=0;c<TCHc;c+=8){
      bf16x8 v8 = *(const bf16x8*)(kp + c);
#pragma unroll
      for(int i=0;i<8;i++) a += b2f(v8[i]) * qs[c+i];
    }
    sc[jj] = a * 0.0625f;   // TCH^-0.5
  }
  float mx = fmaxf(fmaxf(sc[0],sc[1]), fmaxf(sc[2],sc[3]));
#pragma unroll
  for(int off=32; off>0; off>>=1) mx = fmaxf(mx, __shfl_xor(mx, off));
  if((tid&63)==0) red[tid>>6] = mx;
  __syncthreads();
  mx = fmaxf(fmaxf(red[0],red[1]), fmaxf(red[2],red[3]));
  float se = 0.f;
#pragma unroll
  for(int jj=0;jj<4;jj++){
    float e = expf(sc[jj] - mx);
    aw[tid + 256*jj] = e;
    se += e;
  }
#pragma unroll
  for(int off=32; off>0; off>>=1) se += __shfl_xor(se, off);
  if((tid&63)==0) red[4 + (tid>>6)] = se;
  __syncthreads();
  se = red[4]+red[5]+red[6]+red[7];
  float inv = 1.f/se;
#pragma unroll
  for(int jj=0;jj<4;jj++) aw[tid + 256*jj] *= inv;
  __syncthreads();
  float acc = 0.f;
  const short* vp = kv + (size_t)b*Sc*512 + 256 + tid;
  for(int j=0;j<Sc;j++) acc += aw[j] * b2f(vp[(size_t)j*512]);
  ao[(size_t)(b*Mc+m)*TCHc + tid] = f2b(acc);
}

// ---------------- Former MHA: block per (b,h,m), 64 threads ----------------
__global__ __launch_bounds__(64) void former_attn(const short* __restrict__ qkv, short* __restrict__ oa){
  int blk = blockIdx.x;
  int m = blk % Mc; int bh = blk / Mc; int h = bh % Hc; int b = bh / Hc;
  int lane = threadIdx.x;
  __shared__ float qs[HDc];
  __shared__ float aw2[32];
  const short* base = qkv + (size_t)(b*Mc)*(3*TCHc);
  qs[lane] = b2f(base[(size_t)m*3*TCHc + h*HDc + lane]);
  __syncthreads();
  int j = lane & 31;
  const short* kp = base + (size_t)j*3*TCHc + TCHc + h*HDc;
  float s = 0.f;
  for(int d=0; d<HDc; d+=8){
    bf16x8 v8 = *(const bf16x8*)(kp + d);
#pragma unroll
    for(int i=0;i<8;i++) s += b2f(v8[i]) * qs[d+i];
  }
  s *= 0.125f;  // HD^-0.5
  float mx = s;
#pragma unroll
  for(int off=16; off>0; off>>=1) mx = fmaxf(mx, __shfl_xor(mx, off, 32));
  float e = expf(s - mx);
  float se = e;
#pragma unroll
  for(int off=16; off>0; off>>=1) se += __shfl_xor(se, off, 32);
  if(lane < 32) aw2[lane] = e / se;
  __syncthreads();
  float acc = 0.f;
  const short* vp = base + 2*TCHc + h*HDc + lane;
  for(int jj=0; jj<32; jj++) acc += aw2[jj] * b2f(vp[(size_t)jj*3*TCHc]);
  oa[(size_t)(b*Mc+m)*TCHc + h*HDc + lane] = f2b(acc);
}

// ---------------- LayerNorm over 256: f32 in, bf16 out ---------------------
__global__ __launch_bounds__(64) void ln_kernel(const float* __restrict__ X, const float* __restrict__ g,
                                                const float* __restrict__ bb, short* __restrict__ O){
  int row = blockIdx.x, lane = threadIdx.x;
  const float* xp = X + (size_t)row*TCHc;
  float x[4];
#pragma unroll
  for(int j2=0;j2<4;j2++) x[j2] = xp[lane + 64*j2];
  float sm = x[0]+x[1]+x[2]+x[3];
#pragma unroll
  for(int off=32; off>0; off>>=1) sm += __shfl_xor(sm, off);
  float mu = sm * (1.f/256.f);
  float vs = 0.f;
#pragma unroll
  for(int j2=0;j2<4;j2++){ float d = x[j2]-mu; vs += d*d; }
#pragma unroll
  for(int off=32; off>0; off>>=1) vs += __shfl_xor(vs, off);
  float var = vs * (1.f/256.f);
  float rstd = 1.f / sqrtf(var + 1e-5f);
#pragma unroll
  for(int j2=0;j2<4;j2++){
    int c = lane + 64*j2;
    float o = (x[j2]-mu)*rstd*g[c] + bb[c];
    O[(size_t)row*TCHc + c] = f2b(o);
  }
}

extern "C" void kernel_launch(void* const* d_in, const int* in_sizes, int n_in,
                              void* d_out, int out_size, void* d_ws, size_t ws_size,
                              hipStream_t stream){
  const float* xyz  = (const float*)d_in[0];
  const float* x    = (const float*)d_in[1];
  const float* t_in = (const float*)d_in[2];
  const int*   far0 = (const int*)d_in[3];
  const float* Wproj=(const float*)d_in[4];  const float* gproj=(const float*)d_in[5];  const float* bproj=(const float*)d_in[6];
  const float* Wl1 = (const float*)d_in[7];  const float* gl1 = (const float*)d_in[8];  const float* bl1 = (const float*)d_in[9];
  const float* Wl2 = (const float*)d_in[10]; const float* gl2 = (const float*)d_in[11]; const float* bl2 = (const float*)d_in[12];
  const float* Wc1 = (const float*)d_in[13]; const float* gc1 = (const float*)d_in[14]; const float* bc1 = (const float*)d_in[15];
  const float* Wc2 = (const float*)d_in[16]; const float* gc2 = (const float*)d_in[17]; const float* bc2 = (const float*)d_in[18];
  const float* Wq  = (const float*)d_in[19]; const float* Wk  = (const float*)d_in[20]; const float* Wv  = (const float*)d_in[21];
  const float* Wo  = (const float*)d_in[22];
  const float* ln1g= (const float*)d_in[23]; const float* ln1b= (const float*)d_in[24];
  const float* Wqkv= (const float*)d_in[25]; const float* Wao = (const float*)d_in[26];
  const float* ln2g= (const float*)d_in[27]; const float* ln2b= (const float*)d_in[28];
  const float* Wf1 = (const float*)d_in[29]; const float* Wf2 = (const float*)d_in[30];

  char* wsb = (char*)d_ws;
  size_t off = 0;
  auto alloc = [&](size_t bytes)->void*{ void* p = wsb + off; off += (bytes + 255) & ~(size_t)255; return p; };
  int*   fps_i = (int*)alloc((size_t)Bc*Sc*4);
  float* ddb   = (float*)alloc((size_t)Bc*Nc*4);
  int*   knn   = (int*)alloc((size_t)Bc*Sc*Kc*4);
  short* xT    = (short*)alloc((size_t)Bc*Nc*CINc*2);
  // bf16 pool: proj,l1,l2,c1,c2,k,v,q,o,qkv,ao,f1,f2,t
  size_t wbf_elems = (size_t)COUTc*CINc + 4*(size_t)COUTc*COUTc + 2*(size_t)TCHc*COUTc
                   + 2*(size_t)TCHc*TCHc + 3*(size_t)TCHc*TCHc + (size_t)TCHc*TCHc
                   + 2*(size_t)TCHc*TCHc + 2*(size_t)TCHc*TCHc + (size_t)Bc*Mc*TCHc;
  short* wbf   = (short*)alloc(wbf_elems*2);
  short* fbuf  = (short*)alloc((size_t)Bc*Sc*COUTc*2);
  short* rcbuf = (short*)alloc((size_t)Bc*Sc*COUTc*2);
  short* f2buf = (short*)alloc((size_t)Bc*Sc*COUTc*2);
  short* kvbuf = (short*)alloc((size_t)Bc*Sc*512*2);
  short* qbuf  = (short*)alloc((size_t)Bc*Mc*TCHc*2);
  short* a1out = (short*)alloc((size_t)Bc*Mc*TCHc*2);
  float* t1buf = (float*)alloc((size_t)Bc*Mc*TCHc*4);
  short* hnbuf = (short*)alloc((size_t)Bc*Mc*TCHc*2);
  short* qkvb  = (short*)alloc((size_t)Bc*Mc*3*TCHc*2);
  short* a2out = (short*)alloc((size_t)Bc*Mc*TCHc*2);
  float* t2buf = (float*)alloc((size_t)Bc*Mc*TCHc*4);
  short* hn2buf= (short*)alloc((size_t)Bc*Mc*TCHc*2);
  short* g1buf = (short*)alloc((size_t)Bc*Mc*2*TCHc*2);
  size_t full_bytes  = (size_t)Bc*MBAT*COUTc*2;   // ~96 MB
  size_t batch_bytes = (size_t)MBAT*COUTc*2;      // ~12 MB
  bool batched = (off + 2*(full_bytes + 256) <= ws_size);
  short* hbuf = (short*)alloc(batched ? full_bytes : batch_bytes);
  short* rbuf = (short*)alloc(batched ? full_bytes : batch_bytes);
  if(off > ws_size) return;  // insufficient workspace; fail visibly

  short* wproj_bf = wbf;
  short* wl1_bf   = wproj_bf + COUTc*CINc;
  short* wl2_bf   = wl1_bf + COUTc*COUTc;
  short* wc1_bf   = wl2_bf + COUTc*COUTc;
  short* wc2_bf   = wc1_bf + COUTc*COUTc;
  short* wkv_bf   = wc2_bf + COUTc*COUTc;     // [512,256]
  short* wq_bf    = wkv_bf + 2*TCHc*COUTc;
  short* wo_bf    = wq_bf + TCHc*TCHc;
  short* wqkv_bf  = wo_bf + TCHc*TCHc;
  short* wao_bf   = wqkv_bf + 3*TCHc*TCHc;
  short* wf1_bf   = wao_bf + TCHc*TCHc;
  short* wf2_bf   = wf1_bf + 2*TCHc*TCHc;
  short* tbf      = wf2_bf + 2*TCHc*TCHc;     // t_in as bf16

  float* out0 = (float*)d_out;
  float* out1 = out0 + (size_t)Bc*Sc*3;
  float* out2 = out1 + (size_t)Bc*COUTc*Sc;

  // --- prep: fps + transpose_x + weight/t cvt + dd in one launch ---
  prep_kernel<<<PREP_TOTAL, 256, 0, stream>>>(xyz, far0, fps_i, x, xT,
                                              Wproj, Wl1, Wl2, Wc1, Wc2, Wk, Wv,
                                              Wq, Wo, Wqkv, Wao, Wf1, Wf2, t_in, wbf, ddb);
  knn_kernel<<<Bc*Sc, 256, 0, stream>>>(xyz, fps_i, ddb, knn, out0);
  // --- Local (round-10 proven config) ---
  if(batched){
    proj128<<<dim3(COUTc/128, (Bc*MBAT)/128), 256, 0, stream>>>(xT, knn, fps_i, wproj_bf, gproj, bproj, hbuf, 0);
    gemm128<1,1,0,short><<<dim3(COUTc/128, (Bc*MBAT)/128), 256, 0, stream>>>(hbuf, wl1_bf, gl1, bl1, (const short*)nullptr, rbuf, COUTc, COUTc);
    gemm_l2max<<<dim3(COUTc/64, (Bc*MBAT)/48), 192, 0, stream>>>(rbuf, wl2_bf, gl2, bl2, hbuf, fbuf, 0);
  } else {
    for(int b=0; b<Bc; b++){
      proj128<<<dim3(COUTc/128, MBAT/128), 256, 0, stream>>>(xT, knn, fps_i, wproj_bf, gproj, bproj, hbuf, b*MBAT);
      gemm128<1,1,0,short><<<dim3(COUTc/128, MBAT/128), 256, 0, stream>>>(hbuf, wl1_bf, gl1, bl1, (const short*)nullptr, rbuf, COUTc, COUTc);
      gemm_l2max<<<dim3(COUTc/64, MBAT/48), 192, 0, stream>>>(rbuf, wl2_bf, gl2, bl2, hbuf, fbuf, b*MBAT);
    }
  }
  // --- Channel ---
  gemm64d<1,1,0,short,short><<<dim3(COUTc/64, (Bc*Sc)/64), 256, 0, stream>>>(fbuf, wc1_bf, gc1, bc1, (const short*)nullptr, rcbuf, COUTc, COUTc);
  gemm64d<1,1,1,short,short><<<dim3(COUTc/64, (Bc*Sc)/64), 256, 0, stream>>>(rcbuf, wc2_bf, gc2, bc2, fbuf, f2buf, COUTc, COUTc);
  transpose_f<<<dim3(Sc/32, COUTc/32, Bc), 256, 0, stream>>>(f2buf, out1);
  // --- Local2Former ---
  gemm64d<0,0,0,short,short><<<dim3(TCHc/64, (Bc*Mc)/64), 256, 0, stream>>>(tbf, wq_bf, nullptr, nullptr, (const short*)nullptr, qbuf, TCHc, TCHc);
  gemm64d<0,0,0,short,short><<<dim3(512/64, (Bc*Sc)/64), 256, 0, stream>>>(f2buf, wkv_bf, nullptr, nullptr, (const short*)nullptr, kvbuf, 512, COUTc);
  l2f_attn<<<Bc*Mc, 256, 0, stream>>>(qbuf, kvbuf, a1out);
  gemm64d<0,0,1,float,float><<<dim3(TCHc/64, (Bc*Mc)/64), 256, 0, stream>>>(a1out, wo_bf, nullptr, nullptr, t_in, t1buf, TCHc, TCHc);
  // --- Former ---
  ln_kernel<<<Bc*Mc, 64, 0, stream>>>(t1buf, ln1g, ln1b, hnbuf);
  gemm64d<0,0,0,short,short><<<dim3((3*TCHc)/64, (Bc*Mc)/64), 256, 0, stream>>>(hnbuf, wqkv_bf, nullptr, nullptr, (const short*)nullptr, qkvb, 3*TCHc, TCHc);
  former_attn<<<Bc*Hc*Mc, 64, 0, stream>>>(qkvb, a2out);
  gemm64d<0,0,1,float,float><<<dim3(TCHc/64, (Bc*Mc)/64), 256, 0, stream>>>(a2out, wao_bf, nullptr, nullptr, t1buf, t2buf, TCHc, TCHc);
  ln_kernel<<<Bc*Mc, 64, 0, stream>>>(t2buf, ln2g, ln2b, hn2buf);
  gemm64d<0,1,0,short,short><<<dim3((2*TCHc)/64, (Bc*Mc)/64), 256, 0, stream>>>(hn2buf, wf1_bf, nullptr, nullptr, (const short*)nullptr, g1buf, 2*TCHc, TCHc);
  gemm64d<0,0,1,float,float><<<dim3(TCHc/64, (Bc*Mc)/64), 256, 0, stream>>>(g1buf, wf2_bf, nullptr, nullptr, t2buf, out2, TCHc, 2*TCHc);
}

// Round 14
// 1184.799 us; speedup vs baseline: 1.2337x; 1.0221x over previous
//
#include <hip/hip_runtime.h>
#include <math.h>

#define Bc 8
#define Nc 4096
#define CINc 128
#define COUTc 256
#define Sc 1024
#define Kc 24
#define TCHc 256
#define Mc 32
#define Hc 4
#define HDc 64
#define MBAT (Sc*Kc)      // rows per batch in Local stage: 24576

#define BN_SCALE_F 0.9999950000374997f

typedef __attribute__((ext_vector_type(8))) short bf16x8;
typedef __attribute__((ext_vector_type(4))) float f32x4;

__device__ __forceinline__ float b2f(short s){
  unsigned int u = ((unsigned int)(unsigned short)s) << 16;
  union { unsigned int u; float f; } c; c.u = u; return c.f;
}
__device__ __forceinline__ short f2b(float f){
  union { unsigned int u; float f; } c; c.f = f;
  unsigned int u = c.u;
  unsigned int r = (u + 0x7fffu + ((u >> 16) & 1u)) >> 16;
  return (short)(r & 0xffffu);
}
__device__ __forceinline__ float gelu_f(float v){
  return 0.5f * v * (1.f + erff(v * 0.7071067811865475f));
}
__device__ __forceinline__ float rdval(const float* p){ return *p; }
__device__ __forceinline__ float rdval(const short* p){ return b2f(*p); }
__device__ __forceinline__ void wrval(float* p, float v){ *p = v; }
__device__ __forceinline__ void wrval(short* p, float v){ *p = f2b(v); }

// async global->LDS, 16B per lane (dest follows lane order: base + lane*16B)
__device__ __forceinline__ void gl_lds16(const short* g, short* l){
  __builtin_amdgcn_global_load_lds(
     (const __attribute__((address_space(1))) void*)g,
     (__attribute__((address_space(3))) void*)l, 16, 0, 0);
}

template<int CTRL>
__device__ __forceinline__ double dpp_max_f64(double v){
  long long x = __double_as_longlong(v);
  int lo = (int)(unsigned int)(x & 0xFFFFFFFFLL);
  int hi = (int)(unsigned int)((unsigned long long)x >> 32);
  int plo = __builtin_amdgcn_update_dpp(lo, lo, CTRL, 0xF, 0xF, false);
  int phi = __builtin_amdgcn_update_dpp(hi, hi, CTRL, 0xF, 0xF, false);
  double p = __longlong_as_double((long long)(((unsigned long long)(unsigned int)phi << 32)
                                              | (unsigned int)plo));
  return fmax(v, p);
}
template<int CTRL>
__device__ __forceinline__ float dpp_min_f32(float v){
  int x = __float_as_int(v);
  int p = __builtin_amdgcn_update_dpp(x, x, CTRL, 0xF, 0xF, false);
  return fminf(v, __int_as_float(p));
}
template<int CTRL>
__device__ __forceinline__ unsigned dpp_min_u32(unsigned v){
  int p = __builtin_amdgcn_update_dpp((int)v, (int)v, CTRL, 0xF, 0xF, false);
  unsigned pu = (unsigned)p;
  return v < pu ? v : pu;
}

// ------- prep+knn mega-kernel: 256 blocks (1/CU, co-resident by capacity) --
// bid 0..7: FPS (publishes winners progressively). bid 8..255: workers —
// tx/cvt chores, then pipelined KNN gated on fps progress.
#define PREP_FPS 8
#define PREP_TOTAL 256
#define NWORK 248          // 31 workers per batch

__global__ __launch_bounds__(256) void prep_kernel(
    const float* __restrict__ xyz, const int* __restrict__ far0, int* __restrict__ fps_idx,
    const float* __restrict__ x, short* __restrict__ xT,
    const float* __restrict__ Wproj, const float* __restrict__ Wl1, const float* __restrict__ Wl2,
    const float* __restrict__ Wc1, const float* __restrict__ Wc2,
    const float* __restrict__ Wk, const float* __restrict__ Wv,
    const float* __restrict__ Wq, const float* __restrict__ Wo,
    const float* __restrict__ Wqkv, const float* __restrict__ Wao,
    const float* __restrict__ Wf1, const float* __restrict__ Wf2,
    const float* __restrict__ t_in,
    short* __restrict__ wbf, int* __restrict__ prog,
    int* __restrict__ knn_idx, float* __restrict__ out0){
  __shared__ double smem[6176];   // 49408 B: fps sx/sy/sz; workers: tile/qn/pv/pi
  int bid = blockIdx.x, tid = threadIdx.x;
  if(bid < PREP_FPS){
    // ---- FPS (round-6/10 proven logic) + progressive publish ----
    int b = bid;
    float* sx = (float*)smem;
    float* sy = sx + Nc;
    float* sz = sy + Nc;
    double* pwave = smem + (Nc*12)/8;   // [2][4]
    const float* xb = xyz + (size_t)b*Nc*3;
    for(int i=tid; i<Nc; i+=256){
      const float* p = xb + i*3;
      sx[i]=p[0]; sy[i]=p[1]; sz[i]=p[2];
    }
    __syncthreads();
    float px[16], py[16], pz[16], dmin[16];
    unsigned int lokey[16];
#pragma unroll
    for(int j=0;j<16;j++){
      int n = tid + 256*j;
      px[j]=sx[n]; py[j]=sy[n]; pz[j]=sz[n];
      dmin[j]=1e10f;
      lokey[j]=(unsigned int)((Nc-1) - n);
    }
    int winner = far0[b] & (Nc-1);
    int* out = fps_idx + b*Sc;
    for(int it=0; it<Sc; it++){
      if(tid==0){
        __hip_atomic_store(&out[it], winner, __ATOMIC_RELAXED, __HIP_MEMORY_SCOPE_AGENT);
        if((it & 7) == 7)
          __hip_atomic_store(&prog[b], it+1, __ATOMIC_RELEASE, __HIP_MEMORY_SCOPE_AGENT);
      }
      float cx=sx[winner], cy=sy[winner], cz=sz[winner];
      double key[16];
#pragma unroll
      for(int j=0;j<16;j++){
        float dx = __fsub_rn(px[j], cx);
        float dy = __fsub_rn(py[j], cy);
        float dz = __fsub_rn(pz[j], cz);
        float d = __fadd_rn(__fadd_rn(__fmul_rn(dx,dx), __fmul_rn(dy,dy)), __fmul_rn(dz,dz));
        dmin[j] = fminf(dmin[j], d);
        unsigned long long k = (((unsigned long long)__float_as_uint(dmin[j])) << 32) | lokey[j];
        key[j] = __longlong_as_double((long long)k);
      }
#pragma unroll
      for(int st=8; st>0; st>>=1)
#pragma unroll
        for(int j=0;j<st;j++) key[j] = fmax(key[j], key[j+st]);
      double kv = key[0];
      kv = dpp_max_f64<0x111>(kv);
      kv = dpp_max_f64<0x112>(kv);
      kv = dpp_max_f64<0x114>(kv);
      kv = dpp_max_f64<0x118>(kv);
      kv = dpp_max_f64<0x142>(kv);
      kv = dpp_max_f64<0x143>(kv);
      int p = it & 1;
      if((tid & 63) == 63) pwave[p*4 + (tid>>6)] = kv;
      __syncthreads();
      double k0 = pwave[p*4+0], k1 = pwave[p*4+1], k2 = pwave[p*4+2], k3 = pwave[p*4+3];
      double kb = fmax(fmax(k0,k1), fmax(k2,k3));
      unsigned long long kbits = (unsigned long long)__double_as_longlong(kb);
      winner = (Nc-1) - (int)(kbits & 0xFFFFFFFFULL);
    }
  } else {
    int wid = bid - PREP_FPS;       // 0..247
    int b = wid / 31;               // batch of this worker
    int widb = wid % 31;            // worker index within batch
    // ---- chore A: transpose_x tiles, strided over workers ----
    short (*tile)[33] = (short(*)[33])smem;
    for(int t = wid; t < 4096; t += NWORK){
      int bb = t >> 9;
      int rem = t & 511;
      int n0 = (rem & 127) * 32;
      int c0 = (rem >> 7) * 32;
      int tx = tid & 31, ty = tid >> 5;
      __syncthreads();
#pragma unroll
      for(int i=0;i<32;i+=8)
        tile[ty+i][tx] = f2b(x[((size_t)bb*CINc + (c0+ty+i))*Nc + n0+tx]);
      __syncthreads();
#pragma unroll
      for(int i=0;i<32;i+=8)
        xT[((size_t)bb*Nc + (n0+ty+i))*CINc + c0+tx] = tile[tx][ty+i];
    }
    // ---- chore B: weight/t conversion, strided over workers ----
    {
      int gid = wid*256 + tid;
      const int stride = NWORK*256;
      short* p = wbf;
      for(int i=gid; i<COUTc*CINc; i+=stride) p[i] = f2b(Wproj[i]);
      p += COUTc*CINc;
      for(int i=gid; i<COUTc*COUTc; i+=stride) p[i] = f2b(Wl1[i]);
      p += COUTc*COUTc;
      for(int i=gid; i<COUTc*COUTc; i+=stride) p[i] = f2b(Wl2[i]);
      p += COUTc*COUTc;
      for(int i=gid; i<COUTc*COUTc; i+=stride) p[i] = f2b(Wc1[i]);
      p += COUTc*COUTc;
      for(int i=gid; i<COUTc*COUTc; i+=stride) p[i] = f2b(Wc2[i]);
      p += COUTc*COUTc;
      for(int i=gid; i<TCHc*COUTc; i+=stride) p[i] = f2b(Wk[i]);
      p += TCHc*COUTc;
      for(int i=gid; i<TCHc*COUTc; i+=stride) p[i] = f2b(Wv[i]);
      p += TCHc*COUTc;
      for(int i=gid; i<TCHc*TCHc; i+=stride) p[i] = f2b(Wq[i]);
      p += TCHc*TCHc;
      for(int i=gid; i<TCHc*TCHc; i+=stride) p[i] = f2b(Wo[i]);
      p += TCHc*TCHc;
      for(int i=gid; i<3*TCHc*TCHc; i+=stride) p[i] = f2b(Wqkv[i]);
      p += 3*TCHc*TCHc;
      for(int i=gid; i<TCHc*TCHc; i+=stride) p[i] = f2b(Wao[i]);
      p += TCHc*TCHc;
      for(int i=gid; i<2*TCHc*TCHc; i+=stride) p[i] = f2b(Wf1[i]);
      p += 2*TCHc*TCHc;
      for(int i=gid; i<2*TCHc*TCHc; i+=stride) p[i] = f2b(Wf2[i]);
      p += 2*TCHc*TCHc;
      for(int i=gid; i<Bc*Mc*TCHc; i+=stride) p[i] = f2b(t_in[i]);
    }
    // ---- KNN: coords+dd in registers; queries gated on fps progress ----
    int* s_qn = (int*)smem;
    float* pv = (float*)smem + 4;
    int*   pi = (int*)smem + 8;
    const float* xb = xyz + (size_t)b*Nc*3;
    float px[16], py[16], pz[16], db[16];
#pragma unroll
    for(int j=0;j<16;j++){
      int n = tid + 256*j;
      float xx=xb[n*3], yy=xb[n*3+1], zz=xb[n*3+2];
      px[j]=xx; py[j]=yy; pz[j]=zz;
      db[j] = __fadd_rn(__fadd_rn(__fmul_rn(xx,xx),__fmul_rn(yy,yy)),__fmul_rn(zz,zz));
    }
    __syncthreads();
    for(int s = widb; s < Sc; s += 31){
      if(tid==0){
        while((unsigned)__hip_atomic_load(&prog[b], __ATOMIC_ACQUIRE, __HIP_MEMORY_SCOPE_AGENT) <= (unsigned)s)
          __builtin_amdgcn_s_sleep(8);
        int qn = __hip_atomic_load(&fps_idx[b*Sc + s], __ATOMIC_RELAXED, __HIP_MEMORY_SCOPE_AGENT) & (Nc-1);
        s_qn[0] = qn;
      }
      __syncthreads();
      int qn = s_qn[0];
      const float* q = xyz + ((size_t)b*Nc + qn)*3;
      float sx = q[0], sy = q[1], sz = q[2];
      if(tid < 3) out0[((size_t)b*Sc + s)*3 + tid] = q[tid];
      float ss = __fadd_rn(__fadd_rn(__fmul_rn(sx,sx),__fmul_rn(sy,sy)),__fmul_rn(sz,sz));
      float dv[16];
#pragma unroll
      for(int j=0;j<16;j++){
        float e = __fmul_rn(sx,px[j]);
        e = __fadd_rn(e, __fmul_rn(sy,py[j]));
        e = __fadd_rn(e, __fmul_rn(sz,pz[j]));
        dv[j] = __fadd_rn(__fadd_rn(__fmul_rn(-2.f,e), ss), db[j]);
      }
      int* ob = knn_idx + ((size_t)b*Sc + s)*Kc;
      for(int k=0;k<Kc;k++){
        float bvv = dv[0];
#pragma unroll
        for(int j=1;j<16;j++) bvv = fminf(bvv, dv[j]);
        bvv = dpp_min_f32<0x111>(bvv);
        bvv = dpp_min_f32<0x112>(bvv);
        bvv = dpp_min_f32<0x114>(bvv);
        bvv = dpp_min_f32<0x118>(bvv);
        bvv = dpp_min_f32<0x142>(bvv);
        bvv = dpp_min_f32<0x143>(bvv);
        if((tid&63)==63) pv[tid>>6] = bvv;
        __syncthreads();
        float vmin = fminf(fminf(pv[0],pv[1]), fminf(pv[2],pv[3]));
        unsigned bi = 0xFFFFFFFFu;
#pragma unroll
        for(int j=0;j<16;j++){
          unsigned n = (unsigned)(tid + 256*j);
          if(dv[j]==vmin && n < bi) bi = n;
        }
        bi = dpp_min_u32<0x111>(bi);
        bi = dpp_min_u32<0x112>(bi);
        bi = dpp_min_u32<0x114>(bi);
        bi = dpp_min_u32<0x118>(bi);
        bi = dpp_min_u32<0x142>(bi);
        bi = dpp_min_u32<0x143>(bi);
        if((tid&63)==63) pi[tid>>6] = (int)bi;
        __syncthreads();
        unsigned i0=(unsigned)pi[0], i1=(unsigned)pi[1], i2=(unsigned)pi[2], i3=(unsigned)pi[3];
        unsigned m01 = i0<i1?i0:i1, m23 = i2<i3?i2:i3;
        unsigned win = m01<m23?m01:m23;
        if(tid==0) ob[k] = (int)(win & (Nc-1));
#pragma unroll
        for(int j=0;j<16;j++) if((int)win == tid + 256*j) dv[j] = 3.4e38f;
      }
    }
  }
}

// ---------------- 128x128 MFMA GEMM, A/W bf16 ------------------------------
template<int HAS_BN, int HAS_GELU, int HAS_RES, typename TRES>
__global__ __launch_bounds__(256) void gemm128(
    const short* __restrict__ A, const short* __restrict__ W,
    const float* __restrict__ g, const float* __restrict__ bias,
    const TRES* __restrict__ Res, short* __restrict__ Out,
    int Nn, int Kk){
  __shared__ short As[128*32];
  __shared__ short Bs[128*32];
  int bm = blockIdx.y*128, bn = blockIdx.x*128;
  int tid = threadIdx.x;
  int wave = tid>>6, lane = tid&63, quad = lane>>4, l16 = lane&15;
  int wr = (wave>>1)*64, wc = (wave&1)*64;
  f32x4 acc[4][4];
#pragma unroll
  for(int i=0;i<4;i++)
#pragma unroll
    for(int j=0;j<4;j++) acc[i][j] = (f32x4){0.f,0.f,0.f,0.f};
  int sr = tid>>2, scc = (tid&3)*8;
  const short* Ap = A + (size_t)(bm+sr)*Kk + scc;
  const short* Wp = W + (size_t)(bn+sr)*Kk + scc;
  for(int k0=0; k0<Kk; k0+=32){
    gl_lds16(Ap + k0,                    As + tid*8);
    gl_lds16(Ap + k0 + (size_t)64*Kk,    As + 2048 + tid*8);
    gl_lds16(Wp + k0,                    Bs + tid*8);
    gl_lds16(Wp + k0 + (size_t)64*Kk,    Bs + 2048 + tid*8);
    __syncthreads();
    bf16x8 af[4], bfr[4];
#pragma unroll
    for(int mt=0; mt<4; mt++) af[mt]  = *(const bf16x8*)&As[(wr+mt*16+l16)*32 + quad*8];
#pragma unroll
    for(int nt=0; nt<4; nt++) bfr[nt] = *(const bf16x8*)&Bs[(wc+nt*16+l16)*32 + quad*8];
#pragma unroll
    for(int mt=0; mt<4; mt++)
#pragma unroll
      for(int nt=0; nt<4; nt++)
        acc[mt][nt] = __builtin_amdgcn_mfma_f32_16x16x32_bf16(af[mt], bfr[nt], acc[mt][nt], 0, 0, 0);
    __syncthreads();
  }
#pragma unroll
  for(int nt=0; nt<4; nt++){
    int col = bn + wc + nt*16 + l16;
    float gs = 0.f, bs_ = 0.f;
    if(HAS_BN){ gs = g[col] * BN_SCALE_F; bs_ = bias[col]; }
#pragma unroll
    for(int mt=0; mt<4; mt++){
#pragma unroll
      for(int r2=0;r2<4;r2++){
        int row = bm + wr + mt*16 + quad*4 + r2;
        float v = acc[mt][nt][r2];
        if(HAS_BN) v = v*gs + bs_;
        if(HAS_RES) v += rdval(Res + (size_t)row*Nn + col);
        if(HAS_GELU) v = gelu_f(v);
        Out[(size_t)row*Nn + col] = f2b(v);
      }
    }
  }
}

// ------- proj 128x128: gathered edge A, W via DMA; rows offset by R0 -------
__global__ __launch_bounds__(256) void proj128(
    const short* __restrict__ xT, const int* __restrict__ knn_idx, const int* __restrict__ fps_idx,
    const short* __restrict__ W, const float* __restrict__ g, const float* __restrict__ bias,
    short* __restrict__ Out, int R0){
  __shared__ short As[128*32];
  __shared__ short Bs[128*32];
  int bm = blockIdx.y*128, bn = blockIdx.x*128;
  int tid = threadIdx.x;
  int wave = tid>>6, lane = tid&63, quad = lane>>4, l16 = lane&15;
  int wr = (wave>>1)*64, wc = (wave&1)*64;
  f32x4 acc[4][4];
#pragma unroll
  for(int i=0;i<4;i++)
#pragma unroll
    for(int j=0;j<4;j++) acc[i][j] = (f32x4){0.f,0.f,0.f,0.f};
  int sr = tid>>2, scc = (tid&3)*8;
  int Rg0 = R0 + bm + sr, Rg1 = Rg0 + 64;
  int b0 = Rg0 / (Sc*Kc), b1 = Rg1 / (Sc*Kc);
  int nk0 = knn_idx[Rg0] & (Nc-1), nk1 = knn_idx[Rg1] & (Nc-1);
  int nc0 = fps_idx[Rg0 / Kc] & (Nc-1), nc1 = fps_idx[Rg1 / Kc] & (Nc-1);
  const short* pk0 = xT + ((size_t)b0*Nc + nk0)*CINc + scc;
  const short* pc0 = xT + ((size_t)b0*Nc + nc0)*CINc + scc;
  const short* pk1 = xT + ((size_t)b1*Nc + nk1)*CINc + scc;
  const short* pc1 = xT + ((size_t)b1*Nc + nc1)*CINc + scc;
  const short* Wp  = W + (size_t)(bn+sr)*CINc + scc;
  for(int k0=0; k0<CINc; k0+=32){
    gl_lds16(Wp + k0,                      Bs + tid*8);
    gl_lds16(Wp + k0 + (size_t)64*CINc,    Bs + 2048 + tid*8);
    bf16x8 vk = *(const bf16x8*)(pk0 + k0);
    bf16x8 vc = *(const bf16x8*)(pc0 + k0);
    bf16x8 e0, e1;
#pragma unroll
    for(int i=0;i<8;i++) e0[i] = f2b(__fsub_rn(b2f(vk[i]), b2f(vc[i])));
    vk = *(const bf16x8*)(pk1 + k0);
    vc = *(const bf16x8*)(pc1 + k0);
#pragma unroll
    for(int i=0;i<8;i++) e1[i] = f2b(__fsub_rn(b2f(vk[i]), b2f(vc[i])));
    *(bf16x8*)&As[tid*8] = e0;
    *(bf16x8*)&As[2048 + tid*8] = e1;
    __syncthreads();
    bf16x8 af[4], bfr[4];
#pragma unroll
    for(int mt=0; mt<4; mt++) af[mt]  = *(const bf16x8*)&As[(wr+mt*16+l16)*32 + quad*8];
#pragma unroll
    for(int nt=0; nt<4; nt++) bfr[nt] = *(const bf16x8*)&Bs[(wc+nt*16+l16)*32 + quad*8];
#pragma unroll
    for(int mt=0; mt<4; mt++)
#pragma unroll
      for(int nt=0; nt<4; nt++)
        acc[mt][nt] = __builtin_amdgcn_mfma_f32_16x16x32_bf16(af[mt], bfr[nt], acc[mt][nt], 0, 0, 0);
    __syncthreads();
  }
#pragma unroll
  for(int nt=0; nt<4; nt++){
    int col = bn + wc + nt*16 + l16;
    float gs = g[col] * BN_SCALE_F, bs_ = bias[col];
#pragma unroll
    for(int mt=0; mt<4; mt++){
#pragma unroll
      for(int r2=0;r2<4;r2++){
        int row = bm + wr + mt*16 + quad*4 + r2;
        float v = acc[mt][nt][r2]*gs + bs_;
        Out[(size_t)row*COUTc + col] = f2b(gelu_f(v));
      }
    }
  }
}

// -- l2 GEMM + residual + gelu + max over k (BM=48), A & W bf16 via DMA -----
__global__ __launch_bounds__(192) void gemm_l2max(
    const short* __restrict__ A, const short* __restrict__ W,
    const float* __restrict__ g, const float* __restrict__ bias,
    const short* __restrict__ Hres, short* __restrict__ Fout, int R0){
  __shared__ short As[48*32];
  __shared__ short Bs[64*32];
  __shared__ float sm[48][65];
  int bm = blockIdx.y*48, bn = blockIdx.x*64;
  int tid = threadIdx.x;
  int wave = tid >> 6, lane = tid & 63, quad = lane >> 4, l16 = lane & 15;
  f32x4 acc[4];
#pragma unroll
  for(int i=0;i<4;i++) acc[i] = (f32x4){0.f,0.f,0.f,0.f};
  const short* Ap  = A + (size_t)(bm + (tid>>2))*COUTc + (tid&3)*8;
  const short* Wp  = W + (size_t)(bn + (tid>>2))*COUTc + (tid&3)*8;
  const short* Wp2 = W + (size_t)(bn + 48 + (lane>>2))*COUTc + (lane&3)*8;
  for(int k0=0; k0<COUTc; k0+=32){
    gl_lds16(Ap + k0, As + tid*8);
    gl_lds16(Wp + k0, Bs + tid*8);
    if(wave==0) gl_lds16(Wp2 + k0, Bs + 1536 + lane*8);
    __syncthreads();
    bf16x8 a = *(const bf16x8*)&As[(wave*16 + l16)*32 + quad*8];
#pragma unroll
    for(int ct=0; ct<4; ct++){
      bf16x8 bb = *(const bf16x8*)&Bs[(ct*16 + l16)*32 + quad*8];
      acc[ct] = __builtin_amdgcn_mfma_f32_16x16x32_bf16(a, bb, acc[ct], 0, 0, 0);
    }
    __syncthreads();
  }
#pragma unroll
  for(int ct=0; ct<4; ct++){
    int col = bn + ct*16 + l16;
    float gs = g[col] * BN_SCALE_F, bs_ = bias[col];
#pragma unroll
    for(int r2=0;r2<4;r2++){
      int rl = wave*16 + quad*4 + r2;
      float v = acc[ct][r2]*gs + bs_;
      v += b2f(Hres[(size_t)(bm+rl)*COUTc + col]);
      sm[rl][ct*16 + l16] = gelu_f(v);
    }
  }
  __syncthreads();
  if(tid < 128){
    int gl = tid >> 6, col = tid & 63;
    float mx = -3.4e38f;
#pragma unroll
    for(int kk=0; kk<Kc; kk++) mx = fmaxf(mx, sm[gl*Kc + kk][col]);
    int gg = R0/Kc + blockIdx.y*2 + gl;   // global (b*Sc+s)
    Fout[(size_t)gg*COUTc + bn + col] = f2b(mx);
  }
}

// ------- 64x64 MFMA GEMM, A & W bf16, both staged via global_load_lds ------
template<int HAS_BN, int HAS_GELU, int HAS_RES, typename TRES, typename TOUT>
__global__ __launch_bounds__(256) void gemm64d(
    const short* __restrict__ A, const short* __restrict__ W,
    const float* __restrict__ g, const float* __restrict__ bias,
    const TRES* __restrict__ Res, TOUT* __restrict__ Out,
    int Nn, int Kk){
  __shared__ short As[64*32];
  __shared__ short Bs[64*32];
  int bm = blockIdx.y*64, bn = blockIdx.x*64;
  int tid = threadIdx.x;
  int wave = tid >> 6, lane = tid & 63, quad = lane >> 4, l16 = lane & 15;
  f32x4 acc[4];
#pragma unroll
  for(int i=0;i<4;i++) acc[i] = (f32x4){0.f,0.f,0.f,0.f};
  const short* Ap = A + (size_t)(bm + (tid>>2))*Kk + (tid&3)*8;
  const short* Wp = W + (size_t)(bn + (tid>>2))*Kk + (tid&3)*8;
  for(int k0=0; k0<Kk; k0+=32){
    gl_lds16(Ap + k0, As + tid*8);
    gl_lds16(Wp + k0, Bs + tid*8);
    __syncthreads();
    bf16x8 a = *(const bf16x8*)&As[(wave*16 + l16)*32 + quad*8];
#pragma unroll
    for(int ct=0; ct<4; ct++){
      bf16x8 bb = *(const bf16x8*)&Bs[(ct*16 + l16)*32 + quad*8];
      acc[ct] = __builtin_amdgcn_mfma_f32_16x16x32_bf16(a, bb, acc[ct], 0, 0, 0);
    }
    __syncthreads();
  }
#pragma unroll
  for(int ct=0; ct<4; ct++){
    int col = bn + ct*16 + l16;
    float gs = 0.f, bs_ = 0.f;
    if(HAS_BN){ gs = g[col] * BN_SCALE_F; bs_ = bias[col]; }
#pragma unroll
    for(int r2=0;r2<4;r2++){
      int row = bm + wave*16 + quad*4 + r2;
      float v = acc[ct][r2];
      if(HAS_BN) v = v*gs + bs_;
      if(HAS_RES) v += rdval(Res + (size_t)row*Nn + col);
      if(HAS_GELU) v = gelu_f(v);
      wrval(Out + (size_t)row*Nn + col, v);
    }
  }
}

// ---------------- f2 [B,S,C] bf16 -> x_out [B,C,S] f32 ---------------------
__global__ __launch_bounds__(256) void transpose_f(const short* __restrict__ f2, float* __restrict__ out1){
  __shared__ short tile[32][33];
  int b = blockIdx.z;
  int s0 = blockIdx.x*32, c0 = blockIdx.y*32;
  int tx = threadIdx.x & 31, ty = threadIdx.x >> 5;
#pragma unroll
  for(int i=0;i<32;i+=8)
    tile[ty+i][tx] = f2[((size_t)b*Sc + (s0+ty+i))*COUTc + c0+tx];
  __syncthreads();
#pragma unroll
  for(int i=0;i<32;i+=8)
    out1[((size_t)b*COUTc + (c0+ty+i))*Sc + s0+tx] = b2f(tile[tx][ty+i]);
}

// ------- Local2Former attention: block per (b,m); kv packed [row,512] ------
__global__ __launch_bounds__(256) void l2f_attn(
    const short* __restrict__ qb, const short* __restrict__ kv,
    short* __restrict__ ao){
  int blk = blockIdx.x; int b = blk / Mc; int m = blk % Mc;
  int tid = threadIdx.x;
  __shared__ float qs[TCHc];
  __shared__ float aw[Sc];
  __shared__ float red[8];
  qs[tid] = b2f(qb[(size_t)(b*Mc+m)*TCHc + tid]);
  __syncthreads();
  float sc[4];
#pragma unroll
  for(int jj=0;jj<4;jj++){
    int j = tid + 256*jj;
    const short* kp = kv + ((size_t)b*Sc + j)*512;
    float a = 0.f;
    for(int c=0;c<TCHc;c+=8){
      bf16x8 v8 = *(const bf16x8*)(kp + c);
#pragma unroll
      for(int i=0;i<8;i++) a += b2f(v8[i]) * qs[c+i];
    }
    sc[jj] = a * 0.0625f;   // TCH^-0.5
  }
  float mx = fmaxf(fmaxf(sc[0],sc[1]), fmaxf(sc[2],sc[3]));
#pragma unroll
  for(int off=32; off>0; off>>=1) mx = fmaxf(mx, __shfl_xor(mx, off));
  if((tid&63)==0) red[tid>>6] = mx;
  __syncthreads();
  mx = fmaxf(fmaxf(red[0],red[1]), fmaxf(red[2],red[3]));
  float se = 0.f;
#pragma unroll
  for(int jj=0;jj<4;jj++){
    float e = expf(sc[jj] - mx);
    aw[tid + 256*jj] = e;
    se += e;
  }
#pragma unroll
  for(int off=32; off>0; off>>=1) se += __shfl_xor(se, off);
  if((tid&63)==0) red[4 + (tid>>6)] = se;
  __syncthreads();
  se = red[4]+red[5]+red[6]+red[7];
  float inv = 1.f/se;
#pragma unroll
  for(int jj=0;jj<4;jj++) aw[tid + 256*jj] *= inv;
  __syncthreads();
  float acc = 0.f;
  const short* vp = kv + (size_t)b*Sc*512 + 256 + tid;
  for(int j=0;j<Sc;j++) acc += aw[j] * b2f(vp[(size_t)j*512]);
  ao[(size_t)(b*Mc+m)*TCHc + tid] = f2b(acc);
}

// ---------------- Former MHA: block per (b,h,m), 64 threads ----------------
__global__ __launch_bounds__(64) void former_attn(const short* __restrict__ qkv, short* __restrict__ oa){
  int blk = blockIdx.x;
  int m = blk % Mc; int bh = blk / Mc; int h = bh % Hc; int b = bh / Hc;
  int lane = threadIdx.x;
  __shared__ float qs[HDc];
  __shared__ float aw2[32];
  const short* base = qkv + (size_t)(b*Mc)*(3*TCHc);
  qs[lane] = b2f(base[(size_t)m*3*TCHc + h*HDc + lane]);
  __syncthreads();
  int j = lane & 31;
  const short* kp = base + (size_t)j*3*TCHc + TCHc + h*HDc;
  float s = 0.f;
  for(int d=0; d<HDc; d+=8){
    bf16x8 v8 = *(const bf16x8*)(kp + d);
#pragma unroll
    for(int i=0;i<8;i++) s += b2f(v8[i]) * qs[d+i];
  }
  s *= 0.125f;  // HD^-0.5
  float mx = s;
#pragma unroll
  for(int off=16; off>0; off>>=1) mx = fmaxf(mx, __shfl_xor(mx, off, 32));
  float e = expf(s - mx);
  float se = e;
#pragma unroll
  for(int off=16; off>0; off>>=1) se += __shfl_xor(se, off, 32);
  if(lane < 32) aw2[lane] = e / se;
  __syncthreads();
  float acc = 0.f;
  const short* vp = base + 2*TCHc + h*HDc + lane;
  for(int jj=0; jj<32; jj++) acc += aw2[jj] * b2f(vp[(size_t)jj*3*TCHc]);
  oa[(size_t)(b*Mc+m)*TCHc + h*HDc + lane] = f2b(acc);
}

// ---------------- LayerNorm over 256: f32 in, bf16 out ---------------------
__global__ __launch_bounds__(64) void ln_kernel(const float* __restrict__ X, const float* __restrict__ g,
                                                const float* __restrict__ bb, short* __restrict__ O){
  int row = blockIdx.x, lane = threadIdx.x;
  const float* xp = X + (size_t)row*TCHc;
  float x[4];
#pragma unroll
  for(int j2=0;j2<4;j2++) x[j2] = xp[lane + 64*j2];
  float sm = x[0]+x[1]+x[2]+x[3];
#pragma unroll
  for(int off=32; off>0; off>>=1) sm += __shfl_xor(sm, off);
  float mu = sm * (1.f/256.f);
  float vs = 0.f;
#pragma unroll
  for(int j2=0;j2<4;j2++){ float d = x[j2]-mu; vs += d*d; }
#pragma unroll
  for(int off=32; off>0; off>>=1) vs += __shfl_xor(vs, off);
  float var = vs * (1.f/256.f);
  float rstd = 1.f / sqrtf(var + 1e-5f);
#pragma unroll
  for(int j2=0;j2<4;j2++){
    int c = lane + 64*j2;
    float o = (x[j2]-mu)*rstd*g[c] + bb[c];
    O[(size_t)row*TCHc + c] = f2b(o);
  }
}

extern "C" void kernel_launch(void* const* d_in, const int* in_sizes, int n_in,
                              void* d_out, int out_size, void* d_ws, size_t ws_size,
                              hipStream_t stream){
  const float* xyz  = (const float*)d_in[0];
  const float* x    = (const float*)d_in[1];
  const float* t_in = (const float*)d_in[2];
  const int*   far0 = (const int*)d_in[3];
  const float* Wproj=(const float*)d_in[4];  const float* gproj=(const float*)d_in[5];  const float* bproj=(const float*)d_in[6];
  const float* Wl1 = (const float*)d_in[7];  const float* gl1 = (const float*)d_in[8];  const float* bl1 = (const float*)d_in[9];
  const float* Wl2 = (const float*)d_in[10]; const float* gl2 = (const float*)d_in[11]; const float* bl2 = (const float*)d_in[12];
  const float* Wc1 = (const float*)d_in[13]; const float* gc1 = (const float*)d_in[14]; const float* bc1 = (const float*)d_in[15];
  const float* Wc2 = (const float*)d_in[16]; const float* gc2 = (const float*)d_in[17]; const float* bc2 = (const float*)d_in[18];
  const float* Wq  = (const float*)d_in[19]; const float* Wk  = (const float*)d_in[20]; const float* Wv  = (const float*)d_in[21];
  const float* Wo  = (const float*)d_in[22];
  const float* ln1g= (const float*)d_in[23]; const float* ln1b= (const float*)d_in[24];
  const float* Wqkv= (const float*)d_in[25]; const float* Wao = (const float*)d_in[26];
  const float* ln2g= (const float*)d_in[27]; const float* ln2b= (const float*)d_in[28];
  const float* Wf1 = (const float*)d_in[29]; const float* Wf2 = (const float*)d_in[30];

  char* wsb = (char*)d_ws;
  size_t off = 0;
  auto alloc = [&](size_t bytes)->void*{ void* p = wsb + off; off += (bytes + 255) & ~(size_t)255; return p; };
  int*   prog  = (int*)alloc(Bc*4);            // fps progress counters (memset to 0 below)
  int*   fps_i = (int*)alloc((size_t)Bc*Sc*4);
  int*   knn   = (int*)alloc((size_t)Bc*Sc*Kc*4);
  short* xT    = (short*)alloc((size_t)Bc*Nc*CINc*2);
  // bf16 pool: proj,l1,l2,c1,c2,k,v,q,o,qkv,ao,f1,f2,t
  size_t wbf_elems = (size_t)COUTc*CINc + 4*(size_t)COUTc*COUTc + 2*(size_t)TCHc*COUTc
                   + 2*(size_t)TCHc*TCHc + 3*(size_t)TCHc*TCHc + (size_t)TCHc*TCHc
                   + 2*(size_t)TCHc*TCHc + 2*(size_t)TCHc*TCHc + (size_t)Bc*Mc*TCHc;
  short* wbf   = (short*)alloc(wbf_elems*2);
  short* fbuf  = (short*)alloc((size_t)Bc*Sc*COUTc*2);
  short* rcbuf = (short*)alloc((size_t)Bc*Sc*COUTc*2);
  short* f2buf = (short*)alloc((size_t)Bc*Sc*COUTc*2);
  short* kvbuf = (short*)alloc((size_t)Bc*Sc*512*2);
  short* qbuf  = (short*)alloc((size_t)Bc*Mc*TCHc*2);
  short* a1out = (short*)alloc((size_t)Bc*Mc*TCHc*2);
  float* t1buf = (float*)alloc((size_t)Bc*Mc*TCHc*4);
  short* hnbuf = (short*)alloc((size_t)Bc*Mc*TCHc*2);
  short* qkvb  = (short*)alloc((size_t)Bc*Mc*3*TCHc*2);
  short* a2out = (short*)alloc((size_t)Bc*Mc*TCHc*2);
  float* t2buf = (float*)alloc((size_t)Bc*Mc*TCHc*4);
  short* hn2buf= (short*)alloc((size_t)Bc*Mc*TCHc*2);
  short* g1buf = (short*)alloc((size_t)Bc*Mc*2*TCHc*2);
  size_t full_bytes  = (size_t)Bc*MBAT*COUTc*2;   // ~96 MB
  size_t batch_bytes = (size_t)MBAT*COUTc*2;      // ~12 MB
  bool batched = (off + 2*(full_bytes + 256) <= ws_size);
  short* hbuf = (short*)alloc(batched ? full_bytes : batch_bytes);
  short* rbuf = (short*)alloc(batched ? full_bytes : batch_bytes);
  if(off > ws_size) return;  // insufficient workspace; fail visibly

  short* wproj_bf = wbf;
  short* wl1_bf   = wproj_bf + COUTc*CINc;
  short* wl2_bf   = wl1_bf + COUTc*COUTc;
  short* wc1_bf   = wl2_bf + COUTc*COUTc;
  short* wc2_bf   = wc1_bf + COUTc*COUTc;
  short* wkv_bf   = wc2_bf + COUTc*COUTc;     // [512,256]
  short* wq_bf    = wkv_bf + 2*TCHc*COUTc;
  short* wo_bf    = wq_bf + TCHc*TCHc;
  short* wqkv_bf  = wo_bf + TCHc*TCHc;
  short* wao_bf   = wqkv_bf + 3*TCHc*TCHc;
  short* wf1_bf   = wao_bf + TCHc*TCHc;
  short* wf2_bf   = wf1_bf + 2*TCHc*TCHc;
  short* tbf      = wf2_bf + 2*TCHc*TCHc;     // t_in as bf16

  float* out0 = (float*)d_out;
  float* out1 = out0 + (size_t)Bc*Sc*3;
  float* out2 = out1 + (size_t)Bc*COUTc*Sc;

  // --- prep+knn: fps publishes winners; workers do tx/cvt then gated knn ---
  hipMemsetAsync(prog, 0, Bc*4, stream);
  prep_kernel<<<PREP_TOTAL, 256, 0, stream>>>(xyz, far0, fps_i, x, xT,
                                              Wproj, Wl1, Wl2, Wc1, Wc2, Wk, Wv,
                                              Wq, Wo, Wqkv, Wao, Wf1, Wf2, t_in,
                                              wbf, prog, knn, out0);
  // --- Local (round-10 proven config) ---
  if(batched){
    proj128<<<dim3(COUTc/128, (Bc*MBAT)/128), 256, 0, stream>>>(xT, knn, fps_i, wproj_bf, gproj, bproj, hbuf, 0);
    gemm128<1,1,0,short><<<dim3(COUTc/128, (Bc*MBAT)/128), 256, 0, stream>>>(hbuf, wl1_bf, gl1, bl1, (const short*)nullptr, rbuf, COUTc, COUTc);
    gemm_l2max<<<dim3(COUTc/64, (Bc*MBAT)/48), 192, 0, stream>>>(rbuf, wl2_bf, gl2, bl2, hbuf, fbuf, 0);
  } else {
    for(int b=0; b<Bc; b++){
      proj128<<<dim3(COUTc/128, MBAT/128), 256, 0, stream>>>(xT, knn, fps_i, wproj_bf, gproj, bproj, hbuf, b*MBAT);
      gemm128<1,1,0,short><<<dim3(COUTc/128, MBAT/128), 256, 0, stream>>>(hbuf, wl1_bf, gl1, bl1, (const short*)nullptr, rbuf, COUTc, COUTc);
      gemm_l2max<<<dim3(COUTc/64, MBAT/48), 192, 0, stream>>>(rbuf, wl2_bf, gl2, bl2, hbuf, fbuf, b*MBAT);
    }
  }
  // --- Channel ---
  gemm64d<1,1,0,short,short><<<dim3(COUTc/64, (Bc*Sc)/64), 256, 0, stream>>>(fbuf, wc1_bf, gc1, bc1, (const short*)nullptr, rcbuf, COUTc, COUTc);
  gemm64d<1,1,1,short,short><<<dim3(COUTc/64, (Bc*Sc)/64), 256, 0, stream>>>(rcbuf, wc2_bf, gc2, bc2, fbuf, f2buf, COUTc, COUTc);
  transpose_f<<<dim3(Sc/32, COUTc/32, Bc), 256, 0, stream>>>(f2buf, out1);
  // --- Local2Former ---
  gemm64d<0,0,0,short,short><<<dim3(TCHc/64, (Bc*Mc)/64), 256, 0, stream>>>(tbf, wq_bf, nullptr, nullptr, (const short*)nullptr, qbuf, TCHc, TCHc);
  gemm64d<0,0,0,short,short><<<dim3(512/64, (Bc*Sc)/64), 256, 0, stream>>>(f2buf, wkv_bf, nullptr, nullptr, (const short*)nullptr, kvbuf, 512, COUTc);
  l2f_attn<<<Bc*Mc, 256, 0, stream>>>(qbuf, kvbuf, a1out);
  gemm64d<0,0,1,float,float><<<dim3(TCHc/64, (Bc*Mc)/64), 256, 0, stream>>>(a1out, wo_bf, nullptr, nullptr, t_in, t1buf, TCHc, TCHc);
  // --- Former ---
  ln_kernel<<<Bc*Mc, 64, 0, stream>>>(t1buf, ln1g, ln1b, hnbuf);
  gemm64d<0,0,0,short,short><<<dim3((3*TCHc)/64, (Bc*Mc)/64), 256, 0, stream>>>(hnbuf, wqkv_bf, nullptr, nullptr, (const short*)nullptr, qkvb, 3*TCHc, TCHc);
  former_attn<<<Bc*Hc*Mc, 64, 0, stream>>>(qkvb, a2out);
  gemm64d<0,0,1,float,float><<<dim3(TCHc/64, (Bc*Mc)/64), 256, 0, stream>>>(a2out, wao_bf, nullptr, nullptr, t1buf, t2buf, TCHc, TCHc);
  ln_kernel<<<Bc*Mc, 64, 0, stream>>>(t2buf, ln2g, ln2b, hn2buf);
  gemm64d<0,1,0,short,short><<<dim3((2*TCHc)/64, (Bc*Mc)/64), 256, 0, stream>>>(hn2buf, wf1_bf, nullptr, nullptr, (const short*)nullptr, g1buf, 2*TCHc, TCHc);
  gemm64d<0,0,1,float,float><<<dim3(TCHc/64, (Bc*Mc)/64), 256, 0, stream>>>(g1buf, wf2_bf, nullptr, nullptr, t2buf, out2, TCHc, 2*TCHc);
}

// Round 15
// 1159.111 us; speedup vs baseline: 1.2610x; 1.0222x over previous
//
#include <hip/hip_runtime.h>
#include <math.h>

#define Bc 8
#define Nc 4096
#define CINc 128
#define COUTc 256
#define Sc 1024
#define Kc 24
#define TCHc 256
#define Mc 32
#define Hc 4
#define HDc 64
#define MBAT (Sc*Kc)      // rows per batch in Local stage: 24576

#define BN_SCALE_F 0.9999950000374997f

typedef __attribute__((ext_vector_type(8))) short bf16x8;
typedef __attribute__((ext_vector_type(4))) float f32x4;

__device__ __forceinline__ float b2f(short s){
  unsigned int u = ((unsigned int)(unsigned short)s) << 16;
  union { unsigned int u; float f; } c; c.u = u; return c.f;
}
__device__ __forceinline__ short f2b(float f){
  union { unsigned int u; float f; } c; c.f = f;
  unsigned int u = c.u;
  unsigned int r = (u + 0x7fffu + ((u >> 16) & 1u)) >> 16;
  return (short)(r & 0xffffu);
}
__device__ __forceinline__ float gelu_f(float v){
  return 0.5f * v * (1.f + erff(v * 0.7071067811865475f));
}
__device__ __forceinline__ float rdval(const float* p){ return *p; }
__device__ __forceinline__ float rdval(const short* p){ return b2f(*p); }
__device__ __forceinline__ void wrval(float* p, float v){ *p = v; }
__device__ __forceinline__ void wrval(short* p, float v){ *p = f2b(v); }

// async global->LDS, 16B per lane (dest follows lane order: base + lane*16B)
__device__ __forceinline__ void gl_lds16(const short* g, short* l){
  __builtin_amdgcn_global_load_lds(
     (const __attribute__((address_space(1))) void*)g,
     (__attribute__((address_space(3))) void*)l, 16, 0, 0);
}

template<int CTRL>
__device__ __forceinline__ double dpp_max_f64(double v){
  long long x = __double_as_longlong(v);
  int lo = (int)(unsigned int)(x & 0xFFFFFFFFLL);
  int hi = (int)(unsigned int)((unsigned long long)x >> 32);
  int plo = __builtin_amdgcn_update_dpp(lo, lo, CTRL, 0xF, 0xF, false);
  int phi = __builtin_amdgcn_update_dpp(hi, hi, CTRL, 0xF, 0xF, false);
  double p = __longlong_as_double((long long)(((unsigned long long)(unsigned int)phi << 32)
                                              | (unsigned int)plo));
  return fmax(v, p);
}
template<int CTRL>
__device__ __forceinline__ float dpp_min_f32(float v){
  int x = __float_as_int(v);
  int p = __builtin_amdgcn_update_dpp(x, x, CTRL, 0xF, 0xF, false);
  return fminf(v, __int_as_float(p));
}
template<int CTRL>
__device__ __forceinline__ unsigned dpp_min_u32(unsigned v){
  int p = __builtin_amdgcn_update_dpp((int)v, (int)v, CTRL, 0xF, 0xF, false);
  unsigned pu = (unsigned)p;
  return v < pu ? v : pu;
}

// ------- prep+knn mega-kernel: 256 blocks (1/CU, co-resident by capacity) --
// bid 0..7: FPS, publishing each winner via RELAXED agent atomic store into
// fps_idx (pre-memset to -1). bid 8..255: workers — tx/cvt chores, then
// pipelined KNN polling fps_idx directly (the polled word IS the data; no
// release/acquire => no cross-XCD L2 writeback/invalidate storms).
#define PREP_FPS 8
#define PREP_TOTAL 256
#define NWORK 248          // 31 workers per batch

__global__ __launch_bounds__(256) void prep_kernel(
    const float* __restrict__ xyz, const int* __restrict__ far0, int* __restrict__ fps_idx,
    const float* __restrict__ x, short* __restrict__ xT,
    const float* __restrict__ Wproj, const float* __restrict__ Wl1, const float* __restrict__ Wl2,
    const float* __restrict__ Wc1, const float* __restrict__ Wc2,
    const float* __restrict__ Wk, const float* __restrict__ Wv,
    const float* __restrict__ Wq, const float* __restrict__ Wo,
    const float* __restrict__ Wqkv, const float* __restrict__ Wao,
    const float* __restrict__ Wf1, const float* __restrict__ Wf2,
    const float* __restrict__ t_in,
    short* __restrict__ wbf,
    int* __restrict__ knn_idx, float* __restrict__ out0){
  __shared__ double smem[6176];   // 49408 B: fps sx/sy/sz; workers: tile/qn/pv/pi
  int bid = blockIdx.x, tid = threadIdx.x;
  if(bid < PREP_FPS){
    // ---- FPS (round-6/10 proven logic) + relaxed publish ----
    int b = bid;
    float* sx = (float*)smem;
    float* sy = sx + Nc;
    float* sz = sy + Nc;
    double* pwave = smem + (Nc*12)/8;   // [2][4]
    const float* xb = xyz + (size_t)b*Nc*3;
    for(int i=tid; i<Nc; i+=256){
      const float* p = xb + i*3;
      sx[i]=p[0]; sy[i]=p[1]; sz[i]=p[2];
    }
    __syncthreads();
    float px[16], py[16], pz[16], dmin[16];
    unsigned int lokey[16];
#pragma unroll
    for(int j=0;j<16;j++){
      int n = tid + 256*j;
      px[j]=sx[n]; py[j]=sy[n]; pz[j]=sz[n];
      dmin[j]=1e10f;
      lokey[j]=(unsigned int)((Nc-1) - n);
    }
    int winner = far0[b] & (Nc-1);
    int* out = fps_idx + b*Sc;
    for(int it=0; it<Sc; it++){
      if(tid==0)
        __hip_atomic_store(&out[it], winner, __ATOMIC_RELAXED, __HIP_MEMORY_SCOPE_AGENT);
      float cx=sx[winner], cy=sy[winner], cz=sz[winner];
      double key[16];
#pragma unroll
      for(int j=0;j<16;j++){
        float dx = __fsub_rn(px[j], cx);
        float dy = __fsub_rn(py[j], cy);
        float dz = __fsub_rn(pz[j], cz);
        float d = __fadd_rn(__fadd_rn(__fmul_rn(dx,dx), __fmul_rn(dy,dy)), __fmul_rn(dz,dz));
        dmin[j] = fminf(dmin[j], d);
        unsigned long long k = (((unsigned long long)__float_as_uint(dmin[j])) << 32) | lokey[j];
        key[j] = __longlong_as_double((long long)k);
      }
#pragma unroll
      for(int st=8; st>0; st>>=1)
#pragma unroll
        for(int j=0;j<st;j++) key[j] = fmax(key[j], key[j+st]);
      double kv = key[0];
      kv = dpp_max_f64<0x111>(kv);
      kv = dpp_max_f64<0x112>(kv);
      kv = dpp_max_f64<0x114>(kv);
      kv = dpp_max_f64<0x118>(kv);
      kv = dpp_max_f64<0x142>(kv);
      kv = dpp_max_f64<0x143>(kv);
      int p = it & 1;
      if((tid & 63) == 63) pwave[p*4 + (tid>>6)] = kv;
      __syncthreads();
      double k0 = pwave[p*4+0], k1 = pwave[p*4+1], k2 = pwave[p*4+2], k3 = pwave[p*4+3];
      double kb = fmax(fmax(k0,k1), fmax(k2,k3));
      unsigned long long kbits = (unsigned long long)__double_as_longlong(kb);
      winner = (Nc-1) - (int)(kbits & 0xFFFFFFFFULL);
    }
  } else {
    int wid = bid - PREP_FPS;       // 0..247
    int b = wid / 31;               // batch of this worker
    int widb = wid % 31;            // worker index within batch
    // ---- chore A: transpose_x tiles, strided over workers ----
    short (*tile)[33] = (short(*)[33])smem;
    for(int t = wid; t < 4096; t += NWORK){
      int bb = t >> 9;
      int rem = t & 511;
      int n0 = (rem & 127) * 32;
      int c0 = (rem >> 7) * 32;
      int tx = tid & 31, ty = tid >> 5;
      __syncthreads();
#pragma unroll
      for(int i=0;i<32;i+=8)
        tile[ty+i][tx] = f2b(x[((size_t)bb*CINc + (c0+ty+i))*Nc + n0+tx]);
      __syncthreads();
#pragma unroll
      for(int i=0;i<32;i+=8)
        xT[((size_t)bb*Nc + (n0+ty+i))*CINc + c0+tx] = tile[tx][ty+i];
    }
    // ---- chore B: weight/t conversion, strided over workers ----
    {
      int gid = wid*256 + tid;
      const int stride = NWORK*256;
      short* p = wbf;
      for(int i=gid; i<COUTc*CINc; i+=stride) p[i] = f2b(Wproj[i]);
      p += COUTc*CINc;
      for(int i=gid; i<COUTc*COUTc; i+=stride) p[i] = f2b(Wl1[i]);
      p += COUTc*COUTc;
      for(int i=gid; i<COUTc*COUTc; i+=stride) p[i] = f2b(Wl2[i]);
      p += COUTc*COUTc;
      for(int i=gid; i<COUTc*COUTc; i+=stride) p[i] = f2b(Wc1[i]);
      p += COUTc*COUTc;
      for(int i=gid; i<COUTc*COUTc; i+=stride) p[i] = f2b(Wc2[i]);
      p += COUTc*COUTc;
      for(int i=gid; i<TCHc*COUTc; i+=stride) p[i] = f2b(Wk[i]);
      p += TCHc*COUTc;
      for(int i=gid; i<TCHc*COUTc; i+=stride) p[i] = f2b(Wv[i]);
      p += TCHc*COUTc;
      for(int i=gid; i<TCHc*TCHc; i+=stride) p[i] = f2b(Wq[i]);
      p += TCHc*TCHc;
      for(int i=gid; i<TCHc*TCHc; i+=stride) p[i] = f2b(Wo[i]);
      p += TCHc*TCHc;
      for(int i=gid; i<3*TCHc*TCHc; i+=stride) p[i] = f2b(Wqkv[i]);
      p += 3*TCHc*TCHc;
      for(int i=gid; i<TCHc*TCHc; i+=stride) p[i] = f2b(Wao[i]);
      p += TCHc*TCHc;
      for(int i=gid; i<2*TCHc*TCHc; i+=stride) p[i] = f2b(Wf1[i]);
      p += 2*TCHc*TCHc;
      for(int i=gid; i<2*TCHc*TCHc; i+=stride) p[i] = f2b(Wf2[i]);
      p += 2*TCHc*TCHc;
      for(int i=gid; i<Bc*Mc*TCHc; i+=stride) p[i] = f2b(t_in[i]);
    }
    // ---- KNN: coords+dd in registers; queries gated by polling fps_idx ----
    int* s_qn = (int*)smem;
    float* pv = (float*)smem + 4;
    int*   pi = (int*)smem + 8;
    const float* xb = xyz + (size_t)b*Nc*3;
    float px[16], py[16], pz[16], db[16];
#pragma unroll
    for(int j=0;j<16;j++){
      int n = tid + 256*j;
      float xx=xb[n*3], yy=xb[n*3+1], zz=xb[n*3+2];
      px[j]=xx; py[j]=yy; pz[j]=zz;
      db[j] = __fadd_rn(__fadd_rn(__fmul_rn(xx,xx),__fmul_rn(yy,yy)),__fmul_rn(zz,zz));
    }
    __syncthreads();
    for(int s = widb; s < Sc; s += 31){
      if(tid==0){
        int qn;
        for(;;){
          qn = __hip_atomic_load(&fps_idx[b*Sc + s], __ATOMIC_RELAXED, __HIP_MEMORY_SCOPE_AGENT);
          if(qn >= 0) break;
          __builtin_amdgcn_s_sleep(8);
        }
        s_qn[0] = qn & (Nc-1);
      }
      __syncthreads();
      int qn = s_qn[0];
      const float* q = xyz + ((size_t)b*Nc + qn)*3;
      float sx = q[0], sy = q[1], sz = q[2];
      if(tid < 3) out0[((size_t)b*Sc + s)*3 + tid] = q[tid];
      float ss = __fadd_rn(__fadd_rn(__fmul_rn(sx,sx),__fmul_rn(sy,sy)),__fmul_rn(sz,sz));
      float dv[16];
#pragma unroll
      for(int j=0;j<16;j++){
        float e = __fmul_rn(sx,px[j]);
        e = __fadd_rn(e, __fmul_rn(sy,py[j]));
        e = __fadd_rn(e, __fmul_rn(sz,pz[j]));
        dv[j] = __fadd_rn(__fadd_rn(__fmul_rn(-2.f,e), ss), db[j]);
      }
      int* ob = knn_idx + ((size_t)b*Sc + s)*Kc;
      for(int k=0;k<Kc;k++){
        float bvv = dv[0];
#pragma unroll
        for(int j=1;j<16;j++) bvv = fminf(bvv, dv[j]);
        bvv = dpp_min_f32<0x111>(bvv);
        bvv = dpp_min_f32<0x112>(bvv);
        bvv = dpp_min_f32<0x114>(bvv);
        bvv = dpp_min_f32<0x118>(bvv);
        bvv = dpp_min_f32<0x142>(bvv);
        bvv = dpp_min_f32<0x143>(bvv);
        if((tid&63)==63) pv[tid>>6] = bvv;
        __syncthreads();
        float vmin = fminf(fminf(pv[0],pv[1]), fminf(pv[2],pv[3]));
        unsigned bi = 0xFFFFFFFFu;
#pragma unroll
        for(int j=0;j<16;j++){
          unsigned n = (unsigned)(tid + 256*j);
          if(dv[j]==vmin && n < bi) bi = n;
        }
        bi = dpp_min_u32<0x111>(bi);
        bi = dpp_min_u32<0x112>(bi);
        bi = dpp_min_u32<0x114>(bi);
        bi = dpp_min_u32<0x118>(bi);
        bi = dpp_min_u32<0x142>(bi);
        bi = dpp_min_u32<0x143>(bi);
        if((tid&63)==63) pi[tid>>6] = (int)bi;
        __syncthreads();
        unsigned i0=(unsigned)pi[0], i1=(unsigned)pi[1], i2=(unsigned)pi[2], i3=(unsigned)pi[3];
        unsigned m01 = i0<i1?i0:i1, m23 = i2<i3?i2:i3;
        unsigned win = m01<m23?m01:m23;
        if(tid==0) ob[k] = (int)(win & (Nc-1));
#pragma unroll
        for(int j=0;j<16;j++) if((int)win == tid + 256*j) dv[j] = 3.4e38f;
      }
    }
  }
}

// ---------------- 128x128 MFMA GEMM, A/W bf16 ------------------------------
template<int HAS_BN, int HAS_GELU, int HAS_RES, typename TRES>
__global__ __launch_bounds__(256) void gemm128(
    const short* __restrict__ A, const short* __restrict__ W,
    const float* __restrict__ g, const float* __restrict__ bias,
    const TRES* __restrict__ Res, short* __restrict__ Out,
    int Nn, int Kk){
  __shared__ short As[128*32];
  __shared__ short Bs[128*32];
  int bm = blockIdx.y*128, bn = blockIdx.x*128;
  int tid = threadIdx.x;
  int wave = tid>>6, lane = tid&63, quad = lane>>4, l16 = lane&15;
  int wr = (wave>>1)*64, wc = (wave&1)*64;
  f32x4 acc[4][4];
#pragma unroll
  for(int i=0;i<4;i++)
#pragma unroll
    for(int j=0;j<4;j++) acc[i][j] = (f32x4){0.f,0.f,0.f,0.f};
  int sr = tid>>2, scc = (tid&3)*8;
  const short* Ap = A + (size_t)(bm+sr)*Kk + scc;
  const short* Wp = W + (size_t)(bn+sr)*Kk + scc;
  for(int k0=0; k0<Kk; k0+=32){
    gl_lds16(Ap + k0,                    As + tid*8);
    gl_lds16(Ap + k0 + (size_t)64*Kk,    As + 2048 + tid*8);
    gl_lds16(Wp + k0,                    Bs + tid*8);
    gl_lds16(Wp + k0 + (size_t)64*Kk,    Bs + 2048 + tid*8);
    __syncthreads();
    bf16x8 af[4], bfr[4];
#pragma unroll
    for(int mt=0; mt<4; mt++) af[mt]  = *(const bf16x8*)&As[(wr+mt*16+l16)*32 + quad*8];
#pragma unroll
    for(int nt=0; nt<4; nt++) bfr[nt] = *(const bf16x8*)&Bs[(wc+nt*16+l16)*32 + quad*8];
#pragma unroll
    for(int mt=0; mt<4; mt++)
#pragma unroll
      for(int nt=0; nt<4; nt++)
        acc[mt][nt] = __builtin_amdgcn_mfma_f32_16x16x32_bf16(af[mt], bfr[nt], acc[mt][nt], 0, 0, 0);
    __syncthreads();
  }
#pragma unroll
  for(int nt=0; nt<4; nt++){
    int col = bn + wc + nt*16 + l16;
    float gs = 0.f, bs_ = 0.f;
    if(HAS_BN){ gs = g[col] * BN_SCALE_F; bs_ = bias[col]; }
#pragma unroll
    for(int mt=0; mt<4; mt++){
#pragma unroll
      for(int r2=0;r2<4;r2++){
        int row = bm + wr + mt*16 + quad*4 + r2;
        float v = acc[mt][nt][r2];
        if(HAS_BN) v = v*gs + bs_;
        if(HAS_RES) v += rdval(Res + (size_t)row*Nn + col);
        if(HAS_GELU) v = gelu_f(v);
        Out[(size_t)row*Nn + col] = f2b(v);
      }
    }
  }
}

// ------- proj 128x128: gathered edge A, W via DMA; rows offset by R0 -------
__global__ __launch_bounds__(256) void proj128(
    const short* __restrict__ xT, const int* __restrict__ knn_idx, const int* __restrict__ fps_idx,
    const short* __restrict__ W, const float* __restrict__ g, const float* __restrict__ bias,
    short* __restrict__ Out, int R0){
  __shared__ short As[128*32];
  __shared__ short Bs[128*32];
  int bm = blockIdx.y*128, bn = blockIdx.x*128;
  int tid = threadIdx.x;
  int wave = tid>>6, lane = tid&63, quad = lane>>4, l16 = lane&15;
  int wr = (wave>>1)*64, wc = (wave&1)*64;
  f32x4 acc[4][4];
#pragma unroll
  for(int i=0;i<4;i++)
#pragma unroll
    for(int j=0;j<4;j++) acc[i][j] = (f32x4){0.f,0.f,0.f,0.f};
  int sr = tid>>2, scc = (tid&3)*8;
  int Rg0 = R0 + bm + sr, Rg1 = Rg0 + 64;
  int b0 = Rg0 / (Sc*Kc), b1 = Rg1 / (Sc*Kc);
  int nk0 = knn_idx[Rg0] & (Nc-1), nk1 = knn_idx[Rg1] & (Nc-1);
  int nc0 = fps_idx[Rg0 / Kc] & (Nc-1), nc1 = fps_idx[Rg1 / Kc] & (Nc-1);
  const short* pk0 = xT + ((size_t)b0*Nc + nk0)*CINc + scc;
  const short* pc0 = xT + ((size_t)b0*Nc + nc0)*CINc + scc;
  const short* pk1 = xT + ((size_t)b1*Nc + nk1)*CINc + scc;
  const short* pc1 = xT + ((size_t)b1*Nc + nc1)*CINc + scc;
  const short* Wp  = W + (size_t)(bn+sr)*CINc + scc;
  for(int k0=0; k0<CINc; k0+=32){
    gl_lds16(Wp + k0,                      Bs + tid*8);
    gl_lds16(Wp + k0 + (size_t)64*CINc,    Bs + 2048 + tid*8);
    bf16x8 vk = *(const bf16x8*)(pk0 + k0);
    bf16x8 vc = *(const bf16x8*)(pc0 + k0);
    bf16x8 e0, e1;
#pragma unroll
    for(int i=0;i<8;i++) e0[i] = f2b(__fsub_rn(b2f(vk[i]), b2f(vc[i])));
    vk = *(const bf16x8*)(pk1 + k0);
    vc = *(const bf16x8*)(pc1 + k0);
#pragma unroll
    for(int i=0;i<8;i++) e1[i] = f2b(__fsub_rn(b2f(vk[i]), b2f(vc[i])));
    *(bf16x8*)&As[tid*8] = e0;
    *(bf16x8*)&As[2048 + tid*8] = e1;
    __syncthreads();
    bf16x8 af[4], bfr[4];
#pragma unroll
    for(int mt=0; mt<4; mt++) af[mt]  = *(const bf16x8*)&As[(wr+mt*16+l16)*32 + quad*8];
#pragma unroll
    for(int nt=0; nt<4; nt++) bfr[nt] = *(const bf16x8*)&Bs[(wc+nt*16+l16)*32 + quad*8];
#pragma unroll
    for(int mt=0; mt<4; mt++)
#pragma unroll
      for(int nt=0; nt<4; nt++)
        acc[mt][nt] = __builtin_amdgcn_mfma_f32_16x16x32_bf16(af[mt], bfr[nt], acc[mt][nt], 0, 0, 0);
    __syncthreads();
  }
#pragma unroll
  for(int nt=0; nt<4; nt++){
    int col = bn + wc + nt*16 + l16;
    float gs = g[col] * BN_SCALE_F, bs_ = bias[col];
#pragma unroll
    for(int mt=0; mt<4; mt++){
#pragma unroll
      for(int r2=0;r2<4;r2++){
        int row = bm + wr + mt*16 + quad*4 + r2;
        float v = acc[mt][nt][r2]*gs + bs_;
        Out[(size_t)row*COUTc + col] = f2b(gelu_f(v));
      }
    }
  }
}

// -- l2 GEMM + residual + gelu + max over k (BM=48), A & W bf16 via DMA -----
__global__ __launch_bounds__(192) void gemm_l2max(
    const short* __restrict__ A, const short* __restrict__ W,
    const float* __restrict__ g, const float* __restrict__ bias,
    const short* __restrict__ Hres, short* __restrict__ Fout, int R0){
  __shared__ short As[48*32];
  __shared__ short Bs[64*32];
  __shared__ float sm[48][65];
  int bm = blockIdx.y*48, bn = blockIdx.x*64;
  int tid = threadIdx.x;
  int wave = tid >> 6, lane = tid & 63, quad = lane >> 4, l16 = lane & 15;
  f32x4 acc[4];
#pragma unroll
  for(int i=0;i<4;i++) acc[i] = (f32x4){0.f,0.f,0.f,0.f};
  const short* Ap  = A + (size_t)(bm + (tid>>2))*COUTc + (tid&3)*8;
  const short* Wp  = W + (size_t)(bn + (tid>>2))*COUTc + (tid&3)*8;
  const short* Wp2 = W + (size_t)(bn + 48 + (lane>>2))*COUTc + (lane&3)*8;
  for(int k0=0; k0<COUTc; k0+=32){
    gl_lds16(Ap + k0, As + tid*8);
    gl_lds16(Wp + k0, Bs + tid*8);
    if(wave==0) gl_lds16(Wp2 + k0, Bs + 1536 + lane*8);
    __syncthreads();
    bf16x8 a = *(const bf16x8*)&As[(wave*16 + l16)*32 + quad*8];
#pragma unroll
    for(int ct=0; ct<4; ct++){
      bf16x8 bb = *(const bf16x8*)&Bs[(ct*16 + l16)*32 + quad*8];
      acc[ct] = __builtin_amdgcn_mfma_f32_16x16x32_bf16(a, bb, acc[ct], 0, 0, 0);
    }
    __syncthreads();
  }
#pragma unroll
  for(int ct=0; ct<4; ct++){
    int col = bn + ct*16 + l16;
    float gs = g[col] * BN_SCALE_F, bs_ = bias[col];
#pragma unroll
    for(int r2=0;r2<4;r2++){
      int rl = wave*16 + quad*4 + r2;
      float v = acc[ct][r2]*gs + bs_;
      v += b2f(Hres[(size_t)(bm+rl)*COUTc + col]);
      sm[rl][ct*16 + l16] = gelu_f(v);
    }
  }
  __syncthreads();
  if(tid < 128){
    int gl = tid >> 6, col = tid & 63;
    float mx = -3.4e38f;
#pragma unroll
    for(int kk=0; kk<Kc; kk++) mx = fmaxf(mx, sm[gl*Kc + kk][col]);
    int gg = R0/Kc + blockIdx.y*2 + gl;   // global (b*Sc+s)
    Fout[(size_t)gg*COUTc + bn + col] = f2b(mx);
  }
}

// ------- 64x64 MFMA GEMM, A & W bf16, both staged via global_load_lds ------
template<int HAS_BN, int HAS_GELU, int HAS_RES, typename TRES, typename TOUT>
__global__ __launch_bounds__(256) void gemm64d(
    const short* __restrict__ A, const short* __restrict__ W,
    const float* __restrict__ g, const float* __restrict__ bias,
    const TRES* __restrict__ Res, TOUT* __restrict__ Out,
    int Nn, int Kk){
  __shared__ short As[64*32];
  __shared__ short Bs[64*32];
  int bm = blockIdx.y*64, bn = blockIdx.x*64;
  int tid = threadIdx.x;
  int wave = tid >> 6, lane = tid & 63, quad = lane >> 4, l16 = lane & 15;
  f32x4 acc[4];
#pragma unroll
  for(int i=0;i<4;i++) acc[i] = (f32x4){0.f,0.f,0.f,0.f};
  const short* Ap = A + (size_t)(bm + (tid>>2))*Kk + (tid&3)*8;
  const short* Wp = W + (size_t)(bn + (tid>>2))*Kk + (tid&3)*8;
  for(int k0=0; k0<Kk; k0+=32){
    gl_lds16(Ap + k0, As + tid*8);
    gl_lds16(Wp + k0, Bs + tid*8);
    __syncthreads();
    bf16x8 a = *(const bf16x8*)&As[(wave*16 + l16)*32 + quad*8];
#pragma unroll
    for(int ct=0; ct<4; ct++){
      bf16x8 bb = *(const bf16x8*)&Bs[(ct*16 + l16)*32 + quad*8];
      acc[ct] = __builtin_amdgcn_mfma_f32_16x16x32_bf16(a, bb, acc[ct], 0, 0, 0);
    }
    __syncthreads();
  }
#pragma unroll
  for(int ct=0; ct<4; ct++){
    int col = bn + ct*16 + l16;
    float gs = 0.f, bs_ = 0.f;
    if(HAS_BN){ gs = g[col] * BN_SCALE_F; bs_ = bias[col]; }
#pragma unroll
    for(int r2=0;r2<4;r2++){
      int row = bm + wave*16 + quad*4 + r2;
      float v = acc[ct][r2];
      if(HAS_BN) v = v*gs + bs_;
      if(HAS_RES) v += rdval(Res + (size_t)row*Nn + col);
      if(HAS_GELU) v = gelu_f(v);
      wrval(Out + (size_t)row*Nn + col, v);
    }
  }
}

// ---------------- f2 [B,S,C] bf16 -> x_out [B,C,S] f32 ---------------------
__global__ __launch_bounds__(256) void transpose_f(const short* __restrict__ f2, float* __restrict__ out1){
  __shared__ short tile[32][33];
  int b = blockIdx.z;
  int s0 = blockIdx.x*32, c0 = blockIdx.y*32;
  int tx = threadIdx.x & 31, ty = threadIdx.x >> 5;
#pragma unroll
  for(int i=0;i<32;i+=8)
    tile[ty+i][tx] = f2[((size_t)b*Sc + (s0+ty+i))*COUTc + c0+tx];
  __syncthreads();
#pragma unroll
  for(int i=0;i<32;i+=8)
    out1[((size_t)b*COUTc + (c0+ty+i))*Sc + s0+tx] = b2f(tile[tx][ty+i]);
}

// ------- Local2Former attention: block per (b,m); kv packed [row,512] ------
__global__ __launch_bounds__(256) void l2f_attn(
    const short* __restrict__ qb, const short* __restrict__ kv,
    short* __restrict__ ao){
  int blk = blockIdx.x; int b = blk / Mc; int m = blk % Mc;
  int tid = threadIdx.x;
  __shared__ float qs[TCHc];
  __shared__ float aw[Sc];
  __shared__ float red[8];
  qs[tid] = b2f(qb[(size_t)(b*Mc+m)*TCHc + tid]);
  __syncthreads();
  float sc[4];
#pragma unroll
  for(int jj=0;jj<4;jj++){
    int j = tid + 256*jj;
    const short* kp = kv + ((size_t)b*Sc + j)*512;
    float a = 0.f;
    for(int c=0;c<TCHc;c+=8){
      bf16x8 v8 = *(const bf16x8*)(kp + c);
#pragma unroll
      for(int i=0;i<8;i++) a += b2f(v8[i]) * qs[c+i];
    }
    sc[jj] = a * 0.0625f;   // TCH^-0.5
  }
  float mx = fmaxf(fmaxf(sc[0],sc[1]), fmaxf(sc[2],sc[3]));
#pragma unroll
  for(int off=32; off>0; off>>=1) mx = fmaxf(mx, __shfl_xor(mx, off));
  if((tid&63)==0) red[tid>>6] = mx;
  __syncthreads();
  mx = fmaxf(fmaxf(red[0],red[1]), fmaxf(red[2],red[3]));
  float se = 0.f;
#pragma unroll
  for(int jj=0;jj<4;jj++){
    float e = expf(sc[jj] - mx);
    aw[tid + 256*jj] = e;
    se += e;
  }
#pragma unroll
  for(int off=32; off>0; off>>=1) se += __shfl_xor(se, off);
  if((tid&63)==0) red[4 + (tid>>6)] = se;
  __syncthreads();
  se = red[4]+red[5]+red[6]+red[7];
  float inv = 1.f/se;
#pragma unroll
  for(int jj=0;jj<4;jj++) aw[tid + 256*jj] *= inv;
  __syncthreads();
  float acc = 0.f;
  const short* vp = kv + (size_t)b*Sc*512 + 256 + tid;
  for(int j=0;j<Sc;j++) acc += aw[j] * b2f(vp[(size_t)j*512]);
  ao[(size_t)(b*Mc+m)*TCHc + tid] = f2b(acc);
}

// ---------------- Former MHA: block per (b,h,m), 64 threads ----------------
__global__ __launch_bounds__(64) void former_attn(const short* __restrict__ qkv, short* __restrict__ oa){
  int blk = blockIdx.x;
  int m = blk % Mc; int bh = blk / Mc; int h = bh % Hc; int b = bh / Hc;
  int lane = threadIdx.x;
  __shared__ float qs[HDc];
  __shared__ float aw2[32];
  const short* base = qkv + (size_t)(b*Mc)*(3*TCHc);
  qs[lane] = b2f(base[(size_t)m*3*TCHc + h*HDc + lane]);
  __syncthreads();
  int j = lane & 31;
  const short* kp = base + (size_t)j*3*TCHc + TCHc + h*HDc;
  float s = 0.f;
  for(int d=0; d<HDc; d+=8){
    bf16x8 v8 = *(const bf16x8*)(kp + d);
#pragma unroll
    for(int i=0;i<8;i++) s += b2f(v8[i]) * qs[d+i];
  }
  s *= 0.125f;  // HD^-0.5
  float mx = s;
#pragma unroll
  for(int off=16; off>0; off>>=1) mx = fmaxf(mx, __shfl_xor(mx, off, 32));
  float e = expf(s - mx);
  float se = e;
#pragma unroll
  for(int off=16; off>0; off>>=1) se += __shfl_xor(se, off, 32);
  if(lane < 32) aw2[lane] = e / se;
  __syncthreads();
  float acc = 0.f;
  const short* vp = base + 2*TCHc + h*HDc + lane;
  for(int jj=0; jj<32; jj++) acc += aw2[jj] * b2f(vp[(size_t)jj*3*TCHc]);
  oa[(size_t)(b*Mc+m)*TCHc + h*HDc + lane] = f2b(acc);
}

// ---------------- LayerNorm over 256: f32 in, bf16 out ---------------------
__global__ __launch_bounds__(64) void ln_kernel(const float* __restrict__ X, const float* __restrict__ g,
                                                const float* __restrict__ bb, short* __restrict__ O){
  int row = blockIdx.x, lane = threadIdx.x;
  const float* xp = X + (size_t)row*TCHc;
  float x[4];
#pragma unroll
  for(int j2=0;j2<4;j2++) x[j2] = xp[lane + 64*j2];
  float sm = x[0]+x[1]+x[2]+x[3];
#pragma unroll
  for(int off=32; off>0; off>>=1) sm += __shfl_xor(sm, off);
  float mu = sm * (1.f/256.f);
  float vs = 0.f;
#pragma unroll
  for(int j2=0;j2<4;j2++){ float d = x[j2]-mu; vs += d*d; }
#pragma unroll
  for(int off=32; off>0; off>>=1) vs += __shfl_xor(vs, off);
  float var = vs * (1.f/256.f);
  float rstd = 1.f / sqrtf(var + 1e-5f);
#pragma unroll
  for(int j2=0;j2<4;j2++){
    int c = lane + 64*j2;
    float o = (x[j2]-mu)*rstd*g[c] + bb[c];
    O[(size_t)row*TCHc + c] = f2b(o);
  }
}

extern "C" void kernel_launch(void* const* d_in, const int* in_sizes, int n_in,
                              void* d_out, int out_size, void* d_ws, size_t ws_size,
                              hipStream_t stream){
  const float* xyz  = (const float*)d_in[0];
  const float* x    = (const float*)d_in[1];
  const float* t_in = (const float*)d_in[2];
  const int*   far0 = (const int*)d_in[3];
  const float* Wproj=(const float*)d_in[4];  const float* gproj=(const float*)d_in[5];  const float* bproj=(const float*)d_in[6];
  const float* Wl1 = (const float*)d_in[7];  const float* gl1 = (const float*)d_in[8];  const float* bl1 = (const float*)d_in[9];
  const float* Wl2 = (const float*)d_in[10]; const float* gl2 = (const float*)d_in[11]; const float* bl2 = (const float*)d_in[12];
  const float* Wc1 = (const float*)d_in[13]; const float* gc1 = (const float*)d_in[14]; const float* bc1 = (const float*)d_in[15];
  const float* Wc2 = (const float*)d_in[16]; const float* gc2 = (const float*)d_in[17]; const float* bc2 = (const float*)d_in[18];
  const float* Wq  = (const float*)d_in[19]; const float* Wk  = (const float*)d_in[20]; const float* Wv  = (const float*)d_in[21];
  const float* Wo  = (const float*)d_in[22];
  const float* ln1g= (const float*)d_in[23]; const float* ln1b= (const float*)d_in[24];
  const float* Wqkv= (const float*)d_in[25]; const float* Wao = (const float*)d_in[26];
  const float* ln2g= (const float*)d_in[27]; const float* ln2b= (const float*)d_in[28];
  const float* Wf1 = (const float*)d_in[29]; const float* Wf2 = (const float*)d_in[30];

  char* wsb = (char*)d_ws;
  size_t off = 0;
  auto alloc = [&](size_t bytes)->void*{ void* p = wsb + off; off += (bytes + 255) & ~(size_t)255; return p; };
  int*   fps_i = (int*)alloc((size_t)Bc*Sc*4);
  int*   knn   = (int*)alloc((size_t)Bc*Sc*Kc*4);
  short* xT    = (short*)alloc((size_t)Bc*Nc*CINc*2);
  // bf16 pool: proj,l1,l2,c1,c2,k,v,q,o,qkv,ao,f1,f2,t
  size_t wbf_elems = (size_t)COUTc*CINc + 4*(size_t)COUTc*COUTc + 2*(size_t)TCHc*COUTc
                   + 2*(size_t)TCHc*TCHc + 3*(size_t)TCHc*TCHc + (size_t)TCHc*TCHc
                   + 2*(size_t)TCHc*TCHc + 2*(size_t)TCHc*TCHc + (size_t)Bc*Mc*TCHc;
  short* wbf   = (short*)alloc(wbf_elems*2);
  short* fbuf  = (short*)alloc((size_t)Bc*Sc*COUTc*2);
  short* rcbuf = (short*)alloc((size_t)Bc*Sc*COUTc*2);
  short* f2buf = (short*)alloc((size_t)Bc*Sc*COUTc*2);
  short* kvbuf = (short*)alloc((size_t)Bc*Sc*512*2);
  short* qbuf  = (short*)alloc((size_t)Bc*Mc*TCHc*2);
  short* a1out = (short*)alloc((size_t)Bc*Mc*TCHc*2);
  float* t1buf = (float*)alloc((size_t)Bc*Mc*TCHc*4);
  short* hnbuf = (short*)alloc((size_t)Bc*Mc*TCHc*2);
  short* qkvb  = (short*)alloc((size_t)Bc*Mc*3*TCHc*2);
  short* a2out = (short*)alloc((size_t)Bc*Mc*TCHc*2);
  float* t2buf = (float*)alloc((size_t)Bc*Mc*TCHc*4);
  short* hn2buf= (short*)alloc((size_t)Bc*Mc*TCHc*2);
  short* g1buf = (short*)alloc((size_t)Bc*Mc*2*TCHc*2);
  size_t full_bytes  = (size_t)Bc*MBAT*COUTc*2;   // ~96 MB
  size_t batch_bytes = (size_t)MBAT*COUTc*2;      // ~12 MB
  bool batched = (off + 2*(full_bytes + 256) <= ws_size);
  short* hbuf = (short*)alloc(batched ? full_bytes : batch_bytes);
  short* rbuf = (short*)alloc(batched ? full_bytes : batch_bytes);
  if(off > ws_size) return;  // insufficient workspace; fail visibly

  short* wproj_bf = wbf;
  short* wl1_bf   = wproj_bf + COUTc*CINc;
  short* wl2_bf   = wl1_bf + COUTc*COUTc;
  short* wc1_bf   = wl2_bf + COUTc*COUTc;
  short* wc2_bf   = wc1_bf + COUTc*COUTc;
  short* wkv_bf   = wc2_bf + COUTc*COUTc;     // [512,256]
  short* wq_bf    = wkv_bf + 2*TCHc*COUTc;
  short* wo_bf    = wq_bf + TCHc*TCHc;
  short* wqkv_bf  = wo_bf + TCHc*TCHc;
  short* wao_bf   = wqkv_bf + 3*TCHc*TCHc;
  short* wf1_bf   = wao_bf + TCHc*TCHc;
  short* wf2_bf   = wf1_bf + 2*TCHc*TCHc;
  short* tbf      = wf2_bf + 2*TCHc*TCHc;     // t_in as bf16

  float* out0 = (float*)d_out;
  float* out1 = out0 + (size_t)Bc*Sc*3;
  float* out2 = out1 + (size_t)Bc*COUTc*Sc;

  // --- prep+knn: fps publishes winners (relaxed); workers poll fps_idx ---
  hipMemsetAsync(fps_i, 0xFF, (size_t)Bc*Sc*4, stream);   // sentinel: -1 = not yet written
  prep_kernel<<<PREP_TOTAL, 256, 0, stream>>>(xyz, far0, fps_i, x, xT,
                                              Wproj, Wl1, Wl2, Wc1, Wc2, Wk, Wv,
                                              Wq, Wo, Wqkv, Wao, Wf1, Wf2, t_in,
                                              wbf, knn, out0);
  // --- Local (round-10 proven config) ---
  if(batched){
    proj128<<<dim3(COUTc/128, (Bc*MBAT)/128), 256, 0, stream>>>(xT, knn, fps_i, wproj_bf, gproj, bproj, hbuf, 0);
    gemm128<1,1,0,short><<<dim3(COUTc/128, (Bc*MBAT)/128), 256, 0, stream>>>(hbuf, wl1_bf, gl1, bl1, (const short*)nullptr, rbuf, COUTc, COUTc);
    gemm_l2max<<<dim3(COUTc/64, (Bc*MBAT)/48), 192, 0, stream>>>(rbuf, wl2_bf, gl2, bl2, hbuf, fbuf, 0);
  } else {
    for(int b=0; b<Bc; b++){
      proj128<<<dim3(COUTc/128, MBAT/128), 256, 0, stream>>>(xT, knn, fps_i, wproj_bf, gproj, bproj, hbuf, b*MBAT);
      gemm128<1,1,0,short><<<dim3(COUTc/128, MBAT/128), 256, 0, stream>>>(hbuf, wl1_bf, gl1, bl1, (const short*)nullptr, rbuf, COUTc, COUTc);
      gemm_l2max<<<dim3(COUTc/64, MBAT/48), 192, 0, stream>>>(rbuf, wl2_bf, gl2, bl2, hbuf, fbuf, b*MBAT);
    }
  }
  // --- Channel ---
  gemm64d<1,1,0,short,short><<<dim3(COUTc/64, (Bc*Sc)/64), 256, 0, stream>>>(fbuf, wc1_bf, gc1, bc1, (const short*)nullptr, rcbuf, COUTc, COUTc);
  gemm64d<1,1,1,short,short><<<dim3(COUTc/64, (Bc*Sc)/64), 256, 0, stream>>>(rcbuf, wc2_bf, gc2, bc2, fbuf, f2buf, COUTc, COUTc);
  transpose_f<<<dim3(Sc/32, COUTc/32, Bc), 256, 0, stream>>>(f2buf, out1);
  // --- Local2Former ---
  gemm64d<0,0,0,short,short><<<dim3(TCHc/64, (Bc*Mc)/64), 256, 0, stream>>>(tbf, wq_bf, nullptr, nullptr, (const short*)nullptr, qbuf, TCHc, TCHc);
  gemm64d<0,0,0,short,short><<<dim3(512/64, (Bc*Sc)/64), 256, 0, stream>>>(f2buf, wkv_bf, nullptr, nullptr, (const short*)nullptr, kvbuf, 512, COUTc);
  l2f_attn<<<Bc*Mc, 256, 0, stream>>>(qbuf, kvbuf, a1out);
  gemm64d<0,0,1,float,float><<<dim3(TCHc/64, (Bc*Mc)/64), 256, 0, stream>>>(a1out, wo_bf, nullptr, nullptr, t_in, t1buf, TCHc, TCHc);
  // --- Former ---
  ln_kernel<<<Bc*Mc, 64, 0, stream>>>(t1buf, ln1g, ln1b, hnbuf);
  gemm64d<0,0,0,short,short><<<dim3((3*TCHc)/64, (Bc*Mc)/64), 256, 0, stream>>>(hnbuf, wqkv_bf, nullptr, nullptr, (const short*)nullptr, qkvb, 3*TCHc, TCHc);
  former_attn<<<Bc*Hc*Mc, 64, 0, stream>>>(qkvb, a2out);
  gemm64d<0,0,1,float,float><<<dim3(TCHc/64, (Bc*Mc)/64), 256, 0, stream>>>(a2out, wao_bf, nullptr, nullptr, t1buf, t2buf, TCHc, TCHc);
  ln_kernel<<<Bc*Mc, 64, 0, stream>>>(t2buf, ln2g, ln2b, hn2buf);
  gemm64d<0,1,0,short,short><<<dim3((2*TCHc)/64, (Bc*Mc)/64), 256, 0, stream>>>(hn2buf, wf1_bf, nullptr, nullptr, (const short*)nullptr, g1buf, 2*TCHc, TCHc);
  gemm64d<0,0,1,float,float><<<dim3(TCHc/64, (Bc*Mc)/64), 256, 0, stream>>>(g1buf, wf2_bf, nullptr, nullptr, t2buf, out2, TCHc, 2*TCHc);
}